// Round 3
// baseline (2622.431 us; speedup 1.0000x reference)
//
#include <hip/hip_runtime.h>

// MiniS4D: B=16, D=512, N=64 states, L=4096, C=8 chunks of S=512.
// ws layout (floats): p_ar 0, p_ai 32768, p_wr 65536, p_wi 98304,
//                     p_dr 131072, p_di 163840 (dtA re/im)
// bytes: pooled @786432, wbf @819200, yg @1867776 (same footprint as R1).

#define UOFF_POOLED 786432
#define UOFF_WBF    819200
#define UOFF_YG     1867776

typedef __attribute__((ext_vector_type(8))) short short8;
typedef __attribute__((ext_vector_type(4))) float f32x4;
typedef __attribute__((ext_vector_type(2))) float f2;

__device__ __forceinline__ f2 pfma(f2 a, f2 b, f2 c) { return __builtin_elementwise_fma(a, b, c); }
__device__ __forceinline__ f2 splx(f2 v) { return __builtin_shufflevector(v, v, 0, 0); }
__device__ __forceinline__ f2 sply(f2 v) { return __builtin_shufflevector(v, v, 1, 1); }

__device__ __forceinline__ unsigned short f2bf(float f) {
  unsigned int u = __float_as_uint(f);
  u = (u + 0x7FFF + ((u >> 16) & 1)) >> 16;  // RNE
  return (unsigned short)u;
}

// exp(dr*t) * cis(di*t)
__device__ __forceinline__ f2 cexp(float dr, float di, float t) {
  float e = expf(dr * t);
  float ph = di * t;
  return (f2){e * cosf(ph), e * sinf(ph)};
}

// sum over each aligned 8-lane octet via DPP (row_half_mirror, quad xor2, xor1)
__device__ __forceinline__ float octet_sum(float v) {
  float t;
  t = __int_as_float(__builtin_amdgcn_mov_dpp(__float_as_int(v), 0x141, 0xF, 0xF, true));
  v += t;
  t = __int_as_float(__builtin_amdgcn_mov_dpp(__float_as_int(v), 0x4E, 0xF, 0xF, true));
  v += t;
  t = __int_as_float(__builtin_amdgcn_mov_dpp(__float_as_int(v), 0xB1, 0xF, 0xF, true));
  v += t;
  return v;
}

// ---- derived SSM params: A_bar, W=C*B_bar, dtA ------------------------------
__global__ void k_params(const float* __restrict__ log_dt,
                         const float* __restrict__ log_A_real,
                         const float* __restrict__ A_imag,
                         const float* __restrict__ B_re, const float* __restrict__ B_im,
                         const float* __restrict__ C_re, const float* __restrict__ C_im,
                         float* __restrict__ p_ar, float* __restrict__ p_ai,
                         float* __restrict__ p_wr, float* __restrict__ p_wi,
                         float* __restrict__ p_dr, float* __restrict__ p_di) {
  int i = blockIdx.x * blockDim.x + threadIdx.x;   // 0..32767, d = i>>6
  int d = i >> 6;
  float dt  = expf(log_dt[d]);
  float Are = -expf(log_A_real[i]);
  float Aim = A_imag[i];
  float dre = dt * Are, dim = dt * Aim;
  float em  = expf(dre);
  float abr = em * cosf(dim);
  float abi = em * sinf(dim);
  // B_bar = (A_bar - 1)/A * B
  float nr = abr - 1.0f, ni = abi;
  float inv = 1.0f / (Are * Are + Aim * Aim);
  float br = (nr * Are + ni * Aim) * inv;
  float bi = (ni * Are - nr * Aim) * inv;
  float Br = B_re[i], Bi = B_im[i];
  float b2r = br * Br - bi * Bi;
  float b2i = br * Bi + bi * Br;
  float Cr = C_re[i], Ci = C_im[i];
  p_ar[i] = abr; p_ai[i] = abi;
  p_wr[i] = Cr * b2r - Ci * b2i;
  p_wi[i] = Cr * b2i + Ci * b2r;
  p_dr[i] = dre; p_di[i] = dim;
}

// ---- W_out fp32 -> bf16 -----------------------------------------------------
__global__ void k_wcvt(const float* __restrict__ w, unsigned short* __restrict__ wb, int n) {
  int i = blockIdx.x * blockDim.x + threadIdx.x;
  if (i < n) wb[i] = f2bf(w[i]);
}

// ---- chunked SSM scan -------------------------------------------------------
// One wave per (b,d). Octet c (lanes 8c..8c+7) owns chunk c (S=512 steps);
// lane r of the octet owns states n = r*8 .. r*8+7.
// Phase 1: H_c = sum_{m in chunk} A^{m-cS} u[m]   (backward Horner, stable)
// Phase 2: X_start[c] = sum_{c'<=c} A^{(7-c+c')S} H_{c'}  (in-wave shfl combine)
// Phase 3: backward emission: y[i] = Re sum_n W_n X[i]; X[i-1] = A X[i] - A^L u[i]
__global__ __launch_bounds__(256, 4) void k_scan(
    const float* __restrict__ u, const float* __restrict__ Dvec,
    const float* __restrict__ p_ar, const float* __restrict__ p_ai,
    const float* __restrict__ p_wr, const float* __restrict__ p_wi,
    const float* __restrict__ p_dr, const float* __restrict__ p_di,
    unsigned short* __restrict__ yg) {
  int tid = threadIdx.x;
  int lane = tid & 63;
  int g = blockIdx.x * 4 + (tid >> 6);   // (b,d) id 0..8191
  int b = g >> 9, d = g & 511;
  int c = lane >> 3;                     // chunk 0..7
  int r = lane & 7;
  int pbase = d * 64 + r * 8;

  // A_bar coefficient pairs: Ax=(ar,ai), Ay=(-ai,ar)
  f2 Ax[8], Ay[8];
#pragma unroll
  for (int j = 0; j < 8; j += 4) {
    float4 tr = *(const float4*)(p_ar + pbase + j);
    float4 ti = *(const float4*)(p_ai + pbase + j);
    Ax[j+0] = (f2){tr.x, ti.x}; Ay[j+0] = (f2){-ti.x, tr.x};
    Ax[j+1] = (f2){tr.y, ti.y}; Ay[j+1] = (f2){-ti.y, tr.y};
    Ax[j+2] = (f2){tr.z, ti.z}; Ay[j+2] = (f2){-ti.z, tr.z};
    Ax[j+3] = (f2){tr.w, ti.w}; Ay[j+3] = (f2){-ti.w, tr.w};
  }

  const float4* up = (const float4*)(u + (size_t)(b * 512 + d) * 4096 + c * 512);

  // ---- phase 1: local Horner over own chunk (m descending)
  f2 H[8];
#pragma unroll
  for (int j = 0; j < 8; ++j) H[j] = (f2){0.f, 0.f};
  float4 cur = up[127];
  for (int gi = 127; gi >= 0; --gi) {
    float4 nxt = up[gi > 0 ? gi - 1 : 0];
#pragma unroll
    for (int s = 3; s >= 0; --s) {
      float uv = (s == 0) ? cur.x : (s == 1) ? cur.y : (s == 2) ? cur.z : cur.w;
      f2 U = {uv, 0.f};
#pragma unroll
      for (int j = 0; j < 8; ++j)
        H[j] = pfma(Ax[j], splx(H[j]), pfma(Ay[j], sply(H[j]), U));
    }
    cur = nxt;
  }

  // ---- phase 2 setup: AS = A^S, P = A^{(7-c)S}, ALn = -A^L  (closed form)
  f2 AS[8], P[8], ALn[8];
  float k0 = (float)((7 - c) * 512);
#pragma unroll
  for (int j = 0; j < 8; j += 4) {
    float4 tr = *(const float4*)(p_dr + pbase + j);
    float4 ti = *(const float4*)(p_di + pbase + j);
    float drj[4] = {tr.x, tr.y, tr.z, tr.w};
    float dij[4] = {ti.x, ti.y, ti.z, ti.w};
#pragma unroll
    for (int q = 0; q < 4; ++q) {
      AS[j+q] = cexp(drj[q], dij[q], 512.0f);
      P[j+q]  = cexp(drj[q], dij[q], k0);
      f2 al   = cexp(drj[q], dij[q], 4096.0f);
      ALn[j+q] = (f2){-al.x, -al.y};
    }
  }

  // ---- phase 2: X_start = sum_{c2<=c} P_{(c,c2)} * H_{c2}, P advances by AS
  f2 X[8];
#pragma unroll
  for (int j = 0; j < 8; ++j) X[j] = (f2){0.f, 0.f};
  for (int c2 = 0; c2 < 8; ++c2) {
#pragma unroll
    for (int j = 0; j < 8; ++j) {
      float hr = __shfl(H[j].x, c2 * 8 + r, 64);
      float hi = __shfl(H[j].y, c2 * 8 + r, 64);
      if (c2 <= c) {
        X[j].x = fmaf(P[j].x, hr, fmaf(-P[j].y, hi, X[j].x));
        X[j].y = fmaf(P[j].x, hi, fmaf(P[j].y, hr, X[j].y));
        float pr = P[j].x * AS[j].x - P[j].y * AS[j].y;
        float pi = P[j].x * AS[j].y + P[j].y * AS[j].x;
        P[j] = (f2){pr, pi};
      }
    }
  }

  // ---- phase 3 coeffs: Wn = (wr, -wi)
  f2 Wn[8];
#pragma unroll
  for (int j = 0; j < 8; j += 4) {
    float4 tr = *(const float4*)(p_wr + pbase + j);
    float4 ti = *(const float4*)(p_wi + pbase + j);
    Wn[j+0] = (f2){tr.x, -ti.x};
    Wn[j+1] = (f2){tr.y, -ti.y};
    Wn[j+2] = (f2){tr.z, -ti.z};
    Wn[j+3] = (f2){tr.w, -ti.w};
  }
  float Dd = Dvec[d];
  unsigned short* outp = yg + (size_t)b * (4096 * 512) + d;
  int ibase = c * 512;

  // ---- phase 3: backward emission over own chunk
  cur = up[127];
  for (int gi = 127; gi >= 0; --gi) {
    float4 nxt = up[gi > 0 ? gi - 1 : 0];
#pragma unroll
    for (int s = 3; s >= 0; --s) {
      float uv = (s == 0) ? cur.x : (s == 1) ? cur.y : (s == 2) ? cur.z : cur.w;
      f2 Uv = {uv, uv};
      f2 acc = {0.f, 0.f};
#pragma unroll
      for (int j = 0; j < 8; ++j) {
        acc = pfma(Wn[j], X[j], acc);                 // (sum wr*Xr, sum -wi*Xi)
        f2 t = pfma(ALn[j], Uv, (f2){0.f, 0.f});      // -A^L * u
        t = pfma(Ay[j], sply(X[j]), t);
        X[j] = pfma(Ax[j], splx(X[j]), t);
      }
      float a = acc.x + acc.y;
      a = octet_sum(a);
      float y = fmaf(Dd, uv, a);
      float ygl = 0.5f * y * (1.0f + erff(y * 0.70710678118654752f));
      if (r == 0) outp[(size_t)(ibase + gi * 4 + s) * 512] = f2bf(ygl);
    }
    cur = nxt;
  }
}

// ---- 1x1 conv (512->1024) + bias + GLU + sum-over-L, fused ------------------
__global__ __launch_bounds__(256) void k_gemm(
    const unsigned short* __restrict__ wbf, const unsigned short* __restrict__ yg,
    const float* __restrict__ b_out, float* __restrict__ pooled) {
  __shared__ unsigned short lwa[64][88];
  __shared__ unsigned short lwg[64][88];
  __shared__ unsigned short ly[64][88];
  int tid = threadIdx.x;
  int mp0 = blockIdx.x * 64;
  int n0 = blockIdx.y * 64;
  int b = n0 >> 12;
  int wv = tid >> 6, lane = tid & 63;
  int mhalf = wv >> 1, nhalf = wv & 1;
  int lrow = lane & 15, quad = lane >> 4;
  f32x4 accA[2][2], accG[2][2];
#pragma unroll
  for (int mt = 0; mt < 2; ++mt)
#pragma unroll
    for (int nt = 0; nt < 2; ++nt) {
      accA[mt][nt] = (f32x4){0.f, 0.f, 0.f, 0.f};
      accG[mt][nt] = (f32x4){0.f, 0.f, 0.f, 0.f};
    }
  int srow = tid >> 2;
  int scol = (tid & 3) * 16;
  for (int kc = 0; kc < 512; kc += 64) {
    const uint4* pa = (const uint4*)(wbf + (size_t)(mp0 + srow) * 512 + kc + scol);
    const uint4* pg = (const uint4*)(wbf + (size_t)(512 + mp0 + srow) * 512 + kc + scol);
    const uint4* py = (const uint4*)(yg + (size_t)(n0 + srow) * 512 + kc + scol);
    uint4 va0 = pa[0], va1 = pa[1];
    uint4 vg0 = pg[0], vg1 = pg[1];
    uint4 vy0 = py[0], vy1 = py[1];
    *(uint4*)&lwa[srow][scol] = va0; *(uint4*)&lwa[srow][scol + 8] = va1;
    *(uint4*)&lwg[srow][scol] = vg0; *(uint4*)&lwg[srow][scol + 8] = vg1;
    *(uint4*)&ly[srow][scol] = vy0;  *(uint4*)&ly[srow][scol + 8] = vy1;
    __syncthreads();
#pragma unroll
    for (int kb = 0; kb < 2; ++kb) {
      int ko = kb * 32 + quad * 8;
      short8 bf[2], af[2], gf[2];
#pragma unroll
      for (int nt = 0; nt < 2; ++nt)
        bf[nt] = *(const short8*)&ly[nhalf * 32 + nt * 16 + lrow][ko];
#pragma unroll
      for (int mt = 0; mt < 2; ++mt) {
        af[mt] = *(const short8*)&lwa[mhalf * 32 + mt * 16 + lrow][ko];
        gf[mt] = *(const short8*)&lwg[mhalf * 32 + mt * 16 + lrow][ko];
      }
#pragma unroll
      for (int mt = 0; mt < 2; ++mt)
#pragma unroll
        for (int nt = 0; nt < 2; ++nt) {
          accA[mt][nt] = __builtin_amdgcn_mfma_f32_16x16x32_bf16(af[mt], bf[nt], accA[mt][nt], 0, 0, 0);
          accG[mt][nt] = __builtin_amdgcn_mfma_f32_16x16x32_bf16(gf[mt], bf[nt], accG[mt][nt], 0, 0, 0);
        }
    }
    __syncthreads();
  }
#pragma unroll
  for (int mt = 0; mt < 2; ++mt) {
#pragma unroll
    for (int reg = 0; reg < 4; ++reg) {
      int olocal = mhalf * 32 + mt * 16 + quad * 4 + reg;
      float ba = b_out[mp0 + olocal];
      float bg = b_out[512 + mp0 + olocal];
      float h = 0.f;
#pragma unroll
      for (int nt = 0; nt < 2; ++nt) {
        float a = accA[mt][nt][reg] + ba;
        float gv = accG[mt][nt][reg] + bg;
        h += a / (1.0f + __expf(-gv));
      }
#pragma unroll
      for (int off = 1; off < 16; off <<= 1) h += __shfl_xor(h, off, 16);
      if (lrow == 0) atomicAdd(&pooled[b * 512 + mp0 + olocal], h);
    }
  }
}

// ---- decoder ----------------------------------------------------------------
__global__ void k_final(const float* __restrict__ pooled, const float* __restrict__ W_dec,
                        const float* __restrict__ b_dec, float* __restrict__ out) {
  int b = blockIdx.x;
  int lane = threadIdx.x;
  float s = 0.f;
#pragma unroll
  for (int j = 0; j < 8; ++j) s += pooled[b * 512 + lane + 64 * j] * W_dec[lane + 64 * j];
#pragma unroll
  for (int off = 1; off < 64; off <<= 1) s += __shfl_xor(s, off, 64);
  if (lane == 0) out[b] = s * (1.0f / 4096.0f) + b_dec[0];
}

extern "C" void kernel_launch(void* const* d_in, const int* in_sizes, int n_in,
                              void* d_out, int out_size, void* d_ws, size_t ws_size,
                              hipStream_t stream) {
  const float* u          = (const float*)d_in[0];
  const float* log_dt     = (const float*)d_in[1];
  const float* log_A_real = (const float*)d_in[2];
  const float* A_imag     = (const float*)d_in[3];
  const float* B_re       = (const float*)d_in[4];
  const float* B_im       = (const float*)d_in[5];
  const float* C_re       = (const float*)d_in[6];
  const float* C_im       = (const float*)d_in[7];
  const float* Dv         = (const float*)d_in[8];
  const float* W_out      = (const float*)d_in[9];
  const float* b_out      = (const float*)d_in[10];
  const float* W_dec      = (const float*)d_in[11];
  const float* b_dec      = (const float*)d_in[12];

  float* ws = (float*)d_ws;
  float* p_ar = ws;
  float* p_ai = ws + 32768;
  float* p_wr = ws + 65536;
  float* p_wi = ws + 98304;
  float* p_dr = ws + 131072;
  float* p_di = ws + 163840;
  float* pooled = (float*)((char*)d_ws + UOFF_POOLED);
  unsigned short* wbf = (unsigned short*)((char*)d_ws + UOFF_WBF);
  unsigned short* yg = (unsigned short*)((char*)d_ws + UOFF_YG);

  hipMemsetAsync(pooled, 0, 16 * 512 * sizeof(float), stream);
  k_params<<<128, 256, 0, stream>>>(log_dt, log_A_real, A_imag, B_re, B_im, C_re, C_im,
                                    p_ar, p_ai, p_wr, p_wi, p_dr, p_di);
  k_wcvt<<<2048, 256, 0, stream>>>(W_out, wbf, 1024 * 512);
  k_scan<<<2048, 256, 0, stream>>>(u, Dv, p_ar, p_ai, p_wr, p_wi, p_dr, p_di, yg);
  k_gemm<<<dim3(8, 1024), 256, 0, stream>>>(wbf, yg, b_out, pooled);
  k_final<<<16, 64, 0, stream>>>(pooled, W_dec, b_dec, (float*)d_out);
}

// Round 4
// 1098.580 us; speedup vs baseline: 2.3871x; 2.3871x over previous
//
#include <hip/hip_runtime.h>

// MiniS4D: B=16, D=512, N=64 states, L=4096, C=8 chunks of S=512.
// ws byte layout:
//   p_ar 0, p_ai 131072, p_wr 262144, p_wi 393216,
//   p_dr 524288, p_di 655360, p_lr 786432, p_li 917504   (each 32768 f32)
//   pooled @1048576 (32KB), wbf @1081344 (1MB bf16),
//   yg @2129920 (33.55MB bf16, layout (b,l,c)),
//   Hbuf @35684352 (33.55MB float2: (b,chunk,d,n) complex) -> 69.2MB total.

#define UOFF_POOLED 1048576
#define UOFF_WBF    1081344
#define UOFF_YG     2129920
#define UOFF_H      35684352

typedef __attribute__((ext_vector_type(8))) short short8;
typedef __attribute__((ext_vector_type(4))) float f32x4;
typedef __attribute__((ext_vector_type(2))) float f2;

__device__ __forceinline__ f2 pfma(f2 a, f2 b, f2 c) { return __builtin_elementwise_fma(a, b, c); }
__device__ __forceinline__ f2 splx(f2 v) { return __builtin_shufflevector(v, v, 0, 0); }
__device__ __forceinline__ f2 sply(f2 v) { return __builtin_shufflevector(v, v, 1, 1); }

__device__ __forceinline__ unsigned short f2bf(float f) {
  unsigned int u = __float_as_uint(f);
  u = (u + 0x7FFF + ((u >> 16) & 1)) >> 16;  // RNE
  return (unsigned short)u;
}

// exp(dr*t) * cis(di*t)
__device__ __forceinline__ f2 cexp(float dr, float di, float t) {
  float e = expf(dr * t);
  float ph = di * t;
  return (f2){e * cosf(ph), e * sinf(ph)};
}

// sum over each aligned 8-lane octet via DPP (row_half_mirror, quad xor2, xor1)
__device__ __forceinline__ float octet_sum(float v) {
  float t;
  t = __int_as_float(__builtin_amdgcn_mov_dpp(__float_as_int(v), 0x141, 0xF, 0xF, true));
  v += t;
  t = __int_as_float(__builtin_amdgcn_mov_dpp(__float_as_int(v), 0x4E, 0xF, 0xF, true));
  v += t;
  t = __int_as_float(__builtin_amdgcn_mov_dpp(__float_as_int(v), 0xB1, 0xF, 0xF, true));
  v += t;
  return v;
}

// ---- derived SSM params ----------------------------------------------------
__global__ void k_params(const float* __restrict__ log_dt,
                         const float* __restrict__ log_A_real,
                         const float* __restrict__ A_imag,
                         const float* __restrict__ B_re, const float* __restrict__ B_im,
                         const float* __restrict__ C_re, const float* __restrict__ C_im,
                         float* __restrict__ p_ar, float* __restrict__ p_ai,
                         float* __restrict__ p_wr, float* __restrict__ p_wi,
                         float* __restrict__ p_dr, float* __restrict__ p_di,
                         float* __restrict__ p_lr, float* __restrict__ p_li) {
  int i = blockIdx.x * blockDim.x + threadIdx.x;   // 0..32767, d = i>>6
  int d = i >> 6;
  float dt  = expf(log_dt[d]);
  float Are = -expf(log_A_real[i]);
  float Aim = A_imag[i];
  float dre = dt * Are, dim = dt * Aim;
  float em  = expf(dre);
  float abr = em * cosf(dim);
  float abi = em * sinf(dim);
  // B_bar = (A_bar - 1)/A * B
  float nr = abr - 1.0f, ni = abi;
  float inv = 1.0f / (Are * Are + Aim * Aim);
  float br = (nr * Are + ni * Aim) * inv;
  float bi = (ni * Are - nr * Aim) * inv;
  float Br = B_re[i], Bi = B_im[i];
  float b2r = br * Br - bi * Bi;
  float b2i = br * Bi + bi * Br;
  float Cr = C_re[i], Ci = C_im[i];
  p_ar[i] = abr; p_ai[i] = abi;
  p_wr[i] = Cr * b2r - Ci * b2i;
  p_wi[i] = Cr * b2i + Ci * b2r;
  p_dr[i] = dre; p_di[i] = dim;
  float eL = expf(dre * 4096.0f);
  float phL = dim * 4096.0f;
  p_lr[i] = eL * cosf(phL);
  p_li[i] = eL * sinf(phL);
}

// ---- W_out fp32 -> bf16 -----------------------------------------------------
__global__ void k_wcvt(const float* __restrict__ w, unsigned short* __restrict__ wb, int n) {
  int i = blockIdx.x * blockDim.x + threadIdx.x;
  if (i < n) wb[i] = f2bf(w[i]);
}

// ---- K1: chunk-local Horner sums --------------------------------------------
// block = (b, chunk c, d-group of 32); octet o <-> d = dg*32+o; lane r: states 8r..8r+7
// H = sum_{m in chunk} A^{m-cS} u[m]  (backward Horner)
__global__ __launch_bounds__(256, 4) void k_chunk(
    const float* __restrict__ u,
    const float* __restrict__ p_ar, const float* __restrict__ p_ai,
    float2* __restrict__ Hbuf) {
  int tid = threadIdx.x;
  int blk = blockIdx.x;
  int dg = blk & 15, c = (blk >> 4) & 7, b = blk >> 7;
  int o = tid >> 3, r = tid & 7;
  int d = dg * 32 + o;
  int pbase = d * 64 + r * 8;

  f2 Ax[8], Ay[8];
#pragma unroll
  for (int j = 0; j < 8; j += 4) {
    float4 tr = *(const float4*)(p_ar + pbase + j);
    float4 ti = *(const float4*)(p_ai + pbase + j);
    Ax[j+0] = (f2){tr.x, ti.x}; Ay[j+0] = (f2){-ti.x, tr.x};
    Ax[j+1] = (f2){tr.y, ti.y}; Ay[j+1] = (f2){-ti.y, tr.y};
    Ax[j+2] = (f2){tr.z, ti.z}; Ay[j+2] = (f2){-ti.z, tr.z};
    Ax[j+3] = (f2){tr.w, ti.w}; Ay[j+3] = (f2){-ti.w, tr.w};
  }

  const float4* up = (const float4*)(u + (size_t)(b * 512 + d) * 4096 + c * 512);
  f2 H[8];
#pragma unroll
  for (int j = 0; j < 8; ++j) H[j] = (f2){0.f, 0.f};
  float4 cur = up[127];
  for (int gi = 127; gi >= 0; --gi) {
    float4 nxt = up[gi > 0 ? gi - 1 : 0];
#pragma unroll
    for (int s = 3; s >= 0; --s) {
      float uv = (s == 0) ? cur.x : (s == 1) ? cur.y : (s == 2) ? cur.z : cur.w;
      f2 U = {uv, 0.f};
#pragma unroll
      for (int j = 0; j < 8; ++j)
        H[j] = pfma(Ax[j], splx(H[j]), pfma(Ay[j], sply(H[j]), U));
    }
    cur = nxt;
  }
  float2* hp = Hbuf + ((size_t)((b * 8 + c) * 512 + d)) * 64 + r * 8;
#pragma unroll
  for (int j = 0; j < 8; j += 2) {
    float4 v = {H[j].x, H[j].y, H[j+1].x, H[j+1].y};
    *(float4*)(hp + j) = v;
  }
}

// ---- K2: seeds, in place ----------------------------------------------------
// thread per (b,d,n). X_start[c] = A^{(7-c)S} * sum_{c2<=c} A^{c2*S} H_{c2}
__global__ void k_seed(const float* __restrict__ p_dr, const float* __restrict__ p_di,
                       float2* __restrict__ Hbuf) {
  int idx = blockIdx.x * 256 + threadIdx.x;   // (b*512+d)*64 + n
  int n = idx & 63;
  int bd = idx >> 6;
  int d = bd & 511, b = bd >> 9;
  float dr = p_dr[d * 64 + n], di = p_di[d * 64 + n];
  float2* base = Hbuf + ((size_t)(b * 8) * 512 + d) * 64 + n;
  const size_t cs = (size_t)512 * 64;
  f2 H[8];
#pragma unroll
  for (int c = 0; c < 8; ++c) { float2 t = base[c * cs]; H[c] = (f2){t.x, t.y}; }
  f2 G = {0.f, 0.f};
#pragma unroll
  for (int c = 0; c < 8; ++c) {
    f2 acs = cexp(dr, di, (float)(c * 512));
    G.x = fmaf(acs.x, H[c].x, fmaf(-acs.y, H[c].y, G.x));
    G.y = fmaf(acs.x, H[c].y, fmaf(acs.y, H[c].x, G.y));
    f2 rot = cexp(dr, di, (float)((7 - c) * 512));
    float xr = rot.x * G.x - rot.y * G.y;
    float xi = rot.x * G.y + rot.y * G.x;
    base[c * cs] = make_float2(xr, xi);
  }
}

// ---- K3: backward emission --------------------------------------------------
// Same block geometry as K1. y[i] = gelu(Re sum_n W_n X[i] + D*u[i]);
// X[i-1] = A X[i] - A^L u[i]. Writes yg (b,l,c) — 32 consecutive d per block.
__global__ __launch_bounds__(256, 4) void k_emit(
    const float* __restrict__ u, const float* __restrict__ Dvec,
    const float* __restrict__ p_ar, const float* __restrict__ p_ai,
    const float* __restrict__ p_wr, const float* __restrict__ p_wi,
    const float* __restrict__ p_lr, const float* __restrict__ p_li,
    const float2* __restrict__ Xbuf, unsigned short* __restrict__ yg) {
  int tid = threadIdx.x;
  int blk = blockIdx.x;
  int dg = blk & 15, c = (blk >> 4) & 7, b = blk >> 7;
  int o = tid >> 3, r = tid & 7;
  int d = dg * 32 + o;
  int pbase = d * 64 + r * 8;

  f2 Ax[8], Ay[8], Wn[8], ALn[8];
#pragma unroll
  for (int j = 0; j < 8; j += 4) {
    float4 tr = *(const float4*)(p_ar + pbase + j);
    float4 ti = *(const float4*)(p_ai + pbase + j);
    Ax[j+0] = (f2){tr.x, ti.x}; Ay[j+0] = (f2){-ti.x, tr.x};
    Ax[j+1] = (f2){tr.y, ti.y}; Ay[j+1] = (f2){-ti.y, tr.y};
    Ax[j+2] = (f2){tr.z, ti.z}; Ay[j+2] = (f2){-ti.z, tr.z};
    Ax[j+3] = (f2){tr.w, ti.w}; Ay[j+3] = (f2){-ti.w, tr.w};
    float4 wr = *(const float4*)(p_wr + pbase + j);
    float4 wi = *(const float4*)(p_wi + pbase + j);
    Wn[j+0] = (f2){wr.x, -wi.x}; Wn[j+1] = (f2){wr.y, -wi.y};
    Wn[j+2] = (f2){wr.z, -wi.z}; Wn[j+3] = (f2){wr.w, -wi.w};
    float4 lr = *(const float4*)(p_lr + pbase + j);
    float4 li = *(const float4*)(p_li + pbase + j);
    ALn[j+0] = (f2){-lr.x, -li.x}; ALn[j+1] = (f2){-lr.y, -li.y};
    ALn[j+2] = (f2){-lr.z, -li.z}; ALn[j+3] = (f2){-lr.w, -li.w};
  }
  float Dd = Dvec[d];

  // seed X at i = c*512 + 511
  const float2* xp = Xbuf + ((size_t)((b * 8 + c) * 512 + d)) * 64 + r * 8;
  f2 X[8];
#pragma unroll
  for (int j = 0; j < 8; j += 2) {
    float4 v = *(const float4*)(xp + j);
    X[j]   = (f2){v.x, v.y};
    X[j+1] = (f2){v.z, v.w};
  }

  const float4* up = (const float4*)(u + (size_t)(b * 512 + d) * 4096 + c * 512);
  unsigned short* outp = yg + (size_t)b * (4096 * 512) + d;
  int ibase = c * 512;

  float4 cur = up[127];
  for (int gi = 127; gi >= 0; --gi) {
    float4 nxt = up[gi > 0 ? gi - 1 : 0];
#pragma unroll
    for (int s = 3; s >= 0; --s) {
      float uv = (s == 0) ? cur.x : (s == 1) ? cur.y : (s == 2) ? cur.z : cur.w;
      f2 Uv = {uv, uv};
      f2 acc = {0.f, 0.f};
#pragma unroll
      for (int j = 0; j < 8; ++j) {
        acc = pfma(Wn[j], X[j], acc);                 // (sum wr*Xr, sum -wi*Xi)
        f2 t = pfma(ALn[j], Uv, (f2){0.f, 0.f});      // -A^L * u
        t = pfma(Ay[j], sply(X[j]), t);
        X[j] = pfma(Ax[j], splx(X[j]), t);
      }
      float a = acc.x + acc.y;
      a = octet_sum(a);
      float y = fmaf(Dd, uv, a);
      float ygl = 0.5f * y * (1.0f + erff(y * 0.70710678118654752f));
      if (r == 0) outp[(size_t)(ibase + gi * 4 + s) * 512] = f2bf(ygl);
    }
    cur = nxt;
  }
}

// ---- 1x1 conv (512->1024) + bias + GLU + sum-over-L, fused ------------------
__global__ __launch_bounds__(256) void k_gemm(
    const unsigned short* __restrict__ wbf, const unsigned short* __restrict__ yg,
    const float* __restrict__ b_out, float* __restrict__ pooled) {
  __shared__ unsigned short lwa[64][88];
  __shared__ unsigned short lwg[64][88];
  __shared__ unsigned short ly[64][88];
  int tid = threadIdx.x;
  int mp0 = blockIdx.x * 64;
  int n0 = blockIdx.y * 64;
  int b = n0 >> 12;
  int wv = tid >> 6, lane = tid & 63;
  int mhalf = wv >> 1, nhalf = wv & 1;
  int lrow = lane & 15, quad = lane >> 4;
  f32x4 accA[2][2], accG[2][2];
#pragma unroll
  for (int mt = 0; mt < 2; ++mt)
#pragma unroll
    for (int nt = 0; nt < 2; ++nt) {
      accA[mt][nt] = (f32x4){0.f, 0.f, 0.f, 0.f};
      accG[mt][nt] = (f32x4){0.f, 0.f, 0.f, 0.f};
    }
  int srow = tid >> 2;
  int scol = (tid & 3) * 16;
  for (int kc = 0; kc < 512; kc += 64) {
    const uint4* pa = (const uint4*)(wbf + (size_t)(mp0 + srow) * 512 + kc + scol);
    const uint4* pg = (const uint4*)(wbf + (size_t)(512 + mp0 + srow) * 512 + kc + scol);
    const uint4* py = (const uint4*)(yg + (size_t)(n0 + srow) * 512 + kc + scol);
    uint4 va0 = pa[0], va1 = pa[1];
    uint4 vg0 = pg[0], vg1 = pg[1];
    uint4 vy0 = py[0], vy1 = py[1];
    *(uint4*)&lwa[srow][scol] = va0; *(uint4*)&lwa[srow][scol + 8] = va1;
    *(uint4*)&lwg[srow][scol] = vg0; *(uint4*)&lwg[srow][scol + 8] = vg1;
    *(uint4*)&ly[srow][scol] = vy0;  *(uint4*)&ly[srow][scol + 8] = vy1;
    __syncthreads();
#pragma unroll
    for (int kb = 0; kb < 2; ++kb) {
      int ko = kb * 32 + quad * 8;
      short8 bf[2], af[2], gf[2];
#pragma unroll
      for (int nt = 0; nt < 2; ++nt)
        bf[nt] = *(const short8*)&ly[nhalf * 32 + nt * 16 + lrow][ko];
#pragma unroll
      for (int mt = 0; mt < 2; ++mt) {
        af[mt] = *(const short8*)&lwa[mhalf * 32 + mt * 16 + lrow][ko];
        gf[mt] = *(const short8*)&lwg[mhalf * 32 + mt * 16 + lrow][ko];
      }
#pragma unroll
      for (int mt = 0; mt < 2; ++mt)
#pragma unroll
        for (int nt = 0; nt < 2; ++nt) {
          accA[mt][nt] = __builtin_amdgcn_mfma_f32_16x16x32_bf16(af[mt], bf[nt], accA[mt][nt], 0, 0, 0);
          accG[mt][nt] = __builtin_amdgcn_mfma_f32_16x16x32_bf16(gf[mt], bf[nt], accG[mt][nt], 0, 0, 0);
        }
    }
    __syncthreads();
  }
#pragma unroll
  for (int mt = 0; mt < 2; ++mt) {
#pragma unroll
    for (int reg = 0; reg < 4; ++reg) {
      int olocal = mhalf * 32 + mt * 16 + quad * 4 + reg;
      float ba = b_out[mp0 + olocal];
      float bg = b_out[512 + mp0 + olocal];
      float h = 0.f;
#pragma unroll
      for (int nt = 0; nt < 2; ++nt) {
        float a = accA[mt][nt][reg] + ba;
        float gv = accG[mt][nt][reg] + bg;
        h += a / (1.0f + __expf(-gv));
      }
#pragma unroll
      for (int off = 1; off < 16; off <<= 1) h += __shfl_xor(h, off, 16);
      if (lrow == 0) atomicAdd(&pooled[b * 512 + mp0 + olocal], h);
    }
  }
}

// ---- decoder ----------------------------------------------------------------
__global__ void k_final(const float* __restrict__ pooled, const float* __restrict__ W_dec,
                        const float* __restrict__ b_dec, float* __restrict__ out) {
  int b = blockIdx.x;
  int lane = threadIdx.x;
  float s = 0.f;
#pragma unroll
  for (int j = 0; j < 8; ++j) s += pooled[b * 512 + lane + 64 * j] * W_dec[lane + 64 * j];
#pragma unroll
  for (int off = 1; off < 64; off <<= 1) s += __shfl_xor(s, off, 64);
  if (lane == 0) out[b] = s * (1.0f / 4096.0f) + b_dec[0];
}

extern "C" void kernel_launch(void* const* d_in, const int* in_sizes, int n_in,
                              void* d_out, int out_size, void* d_ws, size_t ws_size,
                              hipStream_t stream) {
  const float* u          = (const float*)d_in[0];
  const float* log_dt     = (const float*)d_in[1];
  const float* log_A_real = (const float*)d_in[2];
  const float* A_imag     = (const float*)d_in[3];
  const float* B_re       = (const float*)d_in[4];
  const float* B_im       = (const float*)d_in[5];
  const float* C_re       = (const float*)d_in[6];
  const float* C_im       = (const float*)d_in[7];
  const float* Dv         = (const float*)d_in[8];
  const float* W_out      = (const float*)d_in[9];
  const float* b_out      = (const float*)d_in[10];
  const float* W_dec      = (const float*)d_in[11];
  const float* b_dec      = (const float*)d_in[12];

  float* ws = (float*)d_ws;
  float* p_ar = ws;
  float* p_ai = ws + 32768;
  float* p_wr = ws + 65536;
  float* p_wi = ws + 98304;
  float* p_dr = ws + 131072;
  float* p_di = ws + 163840;
  float* p_lr = ws + 196608;
  float* p_li = ws + 229376;
  float* pooled = (float*)((char*)d_ws + UOFF_POOLED);
  unsigned short* wbf = (unsigned short*)((char*)d_ws + UOFF_WBF);
  unsigned short* yg = (unsigned short*)((char*)d_ws + UOFF_YG);
  float2* Hbuf = (float2*)((char*)d_ws + UOFF_H);

  hipMemsetAsync(pooled, 0, 16 * 512 * sizeof(float), stream);
  k_params<<<128, 256, 0, stream>>>(log_dt, log_A_real, A_imag, B_re, B_im, C_re, C_im,
                                    p_ar, p_ai, p_wr, p_wi, p_dr, p_di, p_lr, p_li);
  k_wcvt<<<2048, 256, 0, stream>>>(W_out, wbf, 1024 * 512);
  k_chunk<<<2048, 256, 0, stream>>>(u, p_ar, p_ai, Hbuf);
  k_seed<<<2048, 256, 0, stream>>>(p_dr, p_di, Hbuf);
  k_emit<<<2048, 256, 0, stream>>>(u, Dv, p_ar, p_ai, p_wr, p_wi, p_lr, p_li, Hbuf, yg);
  k_gemm<<<dim3(8, 1024), 256, 0, stream>>>(wbf, yg, b_out, pooled);
  k_final<<<16, 64, 0, stream>>>(pooled, W_dec, b_dec, (float*)d_out);
}

// Round 5
// 837.350 us; speedup vs baseline: 3.1318x; 1.3120x over previous
//
#include <hip/hip_runtime.h>

// MiniS4D: B=16, D=512, N=64 states, L=4096, C=8 chunks of S=512.
// Pipeline: k_params -> k_wcvt -> k_chunk (H sums + u->bf16) -> k_kc (kernel tail)
//           -> k_seedpack (chunk seeds, bf16) -> k_conv (Toeplitz+seed MFMA, yraw (d,b,l))
//           -> k_tg (transpose + D*u + gelu -> yg (b,l,d)) -> k_gemm (GLU) -> k_final
// ws byte layout (87 MB):
//   [0)          params: p_ar,p_ai,p_wr,p_wi,p_dr,p_di,p_lr,p_li (8 x 131072)
//   [1048576)    pooled 32KB
//   [1081344)    wbf 1MB
//   [2129920)    UBF  u_bf bf16 67.1MB   (ALIAS: yg reuses this region after k_conv)
//   [69238784)   YRAW bf16 67.1MB        (ALIAS: Hbuf float2 33.55MB in first half)
//   [136347648)  seedB bf16 16.8MB
//   [153124864)  Kbuf bf16 0.52MB  -> end 153649152

#define UOFF_POOLED 1048576
#define UOFF_WBF    1081344
#define UOFF_UBF    2129920
#define UOFF_YRAW   69238784
#define UOFF_SEEDB  136347648
#define UOFF_KBUF   153124864

typedef __attribute__((ext_vector_type(8))) short short8;
typedef __attribute__((ext_vector_type(4))) float f32x4;
typedef __attribute__((ext_vector_type(2))) float f2;
typedef unsigned short ushort_t;
typedef unsigned int uint_t;

__device__ __forceinline__ f2 pfma(f2 a, f2 b, f2 c) { return __builtin_elementwise_fma(a, b, c); }
__device__ __forceinline__ f2 splx(f2 v) { return __builtin_shufflevector(v, v, 0, 0); }
__device__ __forceinline__ f2 sply(f2 v) { return __builtin_shufflevector(v, v, 1, 1); }

__device__ __forceinline__ ushort_t f2bf(float f) {
  uint_t u = __float_as_uint(f);
  u = (u + 0x7FFF + ((u >> 16) & 1)) >> 16;  // RNE
  return (ushort_t)u;
}
__device__ __forceinline__ float bf2f(ushort_t v) {
  return __uint_as_float(((uint_t)v) << 16);
}

// exp(dr*t) * cis(di*t)
__device__ __forceinline__ f2 cexp(float dr, float di, float t) {
  float e = expf(dr * t);
  float ph = di * t;
  return (f2){e * cosf(ph), e * sinf(ph)};
}

// ---- derived SSM params ----------------------------------------------------
__global__ void k_params(const float* __restrict__ log_dt,
                         const float* __restrict__ log_A_real,
                         const float* __restrict__ A_imag,
                         const float* __restrict__ B_re, const float* __restrict__ B_im,
                         const float* __restrict__ C_re, const float* __restrict__ C_im,
                         float* __restrict__ p_ar, float* __restrict__ p_ai,
                         float* __restrict__ p_wr, float* __restrict__ p_wi,
                         float* __restrict__ p_dr, float* __restrict__ p_di,
                         float* __restrict__ p_lr, float* __restrict__ p_li) {
  int i = blockIdx.x * blockDim.x + threadIdx.x;   // 0..32767, d = i>>6
  int d = i >> 6;
  float dt  = expf(log_dt[d]);
  float Are = -expf(log_A_real[i]);
  float Aim = A_imag[i];
  float dre = dt * Are, dim = dt * Aim;
  float em  = expf(dre);
  float abr = em * cosf(dim);
  float abi = em * sinf(dim);
  float nr = abr - 1.0f, ni = abi;
  float inv = 1.0f / (Are * Are + Aim * Aim);
  float br = (nr * Are + ni * Aim) * inv;
  float bi = (ni * Are - nr * Aim) * inv;
  float Br = B_re[i], Bi = B_im[i];
  float b2r = br * Br - bi * Bi;
  float b2i = br * Bi + bi * Br;
  float Cr = C_re[i], Ci = C_im[i];
  p_ar[i] = abr; p_ai[i] = abi;
  p_wr[i] = Cr * b2r - Ci * b2i;
  p_wi[i] = Cr * b2i + Ci * b2r;
  p_dr[i] = dre; p_di[i] = dim;
  float eL = expf(dre * 4096.0f);
  float phL = dim * 4096.0f;
  p_lr[i] = eL * cosf(phL);
  p_li[i] = eL * sinf(phL);
}

// ---- W_out fp32 -> bf16 -----------------------------------------------------
__global__ void k_wcvt(const float* __restrict__ w, ushort_t* __restrict__ wb, int n) {
  int i = blockIdx.x * blockDim.x + threadIdx.x;
  if (i < n) wb[i] = f2bf(w[i]);
}

// ---- K1: chunk-local Horner sums (+ u->bf16 side write) ---------------------
// block = (b, chunk c, d-group of 32); octet o <-> d = dg*32+o; lane r: states 8r..8r+7
// H = sum_{t<512} A^t u[cS+t]  (backward Horner)
__global__ __launch_bounds__(256, 4) void k_chunk(
    const float* __restrict__ u,
    const float* __restrict__ p_ar, const float* __restrict__ p_ai,
    float2* __restrict__ Hbuf, ushort_t* __restrict__ u_bf) {
  int tid = threadIdx.x;
  int blk = blockIdx.x;
  int dg = blk & 15, c = (blk >> 4) & 7, b = blk >> 7;
  int o = tid >> 3, r = tid & 7;
  int d = dg * 32 + o;
  int pbase = d * 64 + r * 8;

  f2 Ax[8], Ay[8];
#pragma unroll
  for (int j = 0; j < 8; j += 4) {
    float4 tr = *(const float4*)(p_ar + pbase + j);
    float4 ti = *(const float4*)(p_ai + pbase + j);
    Ax[j+0] = (f2){tr.x, ti.x}; Ay[j+0] = (f2){-ti.x, tr.x};
    Ax[j+1] = (f2){tr.y, ti.y}; Ay[j+1] = (f2){-ti.y, tr.y};
    Ax[j+2] = (f2){tr.z, ti.z}; Ay[j+2] = (f2){-ti.z, tr.z};
    Ax[j+3] = (f2){tr.w, ti.w}; Ay[j+3] = (f2){-ti.w, tr.w};
  }

  size_t ubase = (size_t)(b * 512 + d) * 4096 + c * 512;
  const float4* up = (const float4*)(u + ubase);
  f2 H[8];
#pragma unroll
  for (int j = 0; j < 8; ++j) H[j] = (f2){0.f, 0.f};
  float4 cur = up[127];
  for (int gi = 127; gi >= 0; --gi) {
    float4 nxt = up[gi > 0 ? gi - 1 : 0];
    if (r == 0) {  // side write: u in bf16 (coalesces across octets via L2 merge)
      uint_t lo = (uint_t)f2bf(cur.x) | ((uint_t)f2bf(cur.y) << 16);
      uint_t hi = (uint_t)f2bf(cur.z) | ((uint_t)f2bf(cur.w) << 16);
      uint2 vv = {lo, hi};
      *(uint2*)(u_bf + ubase + gi * 4) = vv;
    }
#pragma unroll
    for (int s = 3; s >= 0; --s) {
      float uv = (s == 0) ? cur.x : (s == 1) ? cur.y : (s == 2) ? cur.z : cur.w;
      f2 U = {uv, 0.f};
#pragma unroll
      for (int j = 0; j < 8; ++j)
        H[j] = pfma(Ax[j], splx(H[j]), pfma(Ay[j], sply(H[j]), U));
    }
    cur = nxt;
  }
  float2* hp = Hbuf + ((size_t)((b * 8 + c) * 512 + d)) * 64 + r * 8;
#pragma unroll
  for (int j = 0; j < 8; j += 2) {
    float4 v = {H[j].x, H[j].y, H[j+1].x, H[j+1].y};
    *(float4*)(hp + j) = v;
  }
}

// ---- K2: kernel tail Kbuf[d][x] = K[3584+x] = Re sum_n W_n A^(3584+x), bf16 --
__global__ __launch_bounds__(64) void k_kc(
    const float* __restrict__ p_ar, const float* __restrict__ p_ai,
    const float* __restrict__ p_wr, const float* __restrict__ p_wi,
    const float* __restrict__ p_dr, const float* __restrict__ p_di,
    ushort_t* __restrict__ Kbuf) {
  int d = blockIdx.x;
  int n = threadIdx.x;
  int i = d * 64 + n;
  float ar = p_ar[i], ai = p_ai[i];
  float wr = p_wr[i], wi = p_wi[i];
  f2 e = cexp(p_dr[i], p_di[i], 3584.0f);
  float zr = wr * e.x - wi * e.y;
  float zi = wr * e.y + wi * e.x;
  for (int x = 0; x < 512; ++x) {
    float s = zr;
#pragma unroll
    for (int off = 1; off < 64; off <<= 1) s += __shfl_xor(s, off, 64);
    if (n == 0) Kbuf[d * 512 + x] = f2bf(s);
    float tr = zr * ar - zi * ai;
    zi = zr * ai + zi * ar;
    zr = tr;
  }
}

// ---- K3: seeds. s[c] = A^((7-c)S) * F[cS-1], F excl own chunk. --------------
// seedB[d][col=b*8+c][k'=2n re, 2n+1 im] bf16, k' contiguous for MFMA B-frags.
__global__ __launch_bounds__(256) void k_seedpack(
    const float* __restrict__ p_dr, const float* __restrict__ p_di,
    const float2* __restrict__ Hbuf, ushort_t* __restrict__ seedB) {
  __shared__ ushort_t tile[128 * 128];
  int d = blockIdx.x;
  int tid = threadIdx.x;
  int n = tid >> 2;      // 0..63
  int bq = tid & 3;
  float dr = p_dr[d * 64 + n], di = p_di[d * 64 + n];
  f2 AS = cexp(dr, di, 512.0f);
  f2 R[8];
  R[0] = (f2){1.f, 0.f};
#pragma unroll
  for (int c = 1; c < 8; ++c)
    R[c] = (f2){R[c-1].x * AS.x - R[c-1].y * AS.y, R[c-1].x * AS.y + R[c-1].y * AS.x};
  for (int bb = 0; bb < 4; ++bb) {
    int b = bq * 4 + bb;
    f2 G = {0.f, 0.f};
#pragma unroll
    for (int c = 0; c < 8; ++c) {
      f2 T = R[7 - c];
      float sr = T.x * G.x - T.y * G.y;
      float si = T.x * G.y + T.y * G.x;
      int col = b * 8 + c;
      tile[col * 128 + 2 * n]     = f2bf(sr);
      tile[col * 128 + 2 * n + 1] = f2bf(si);
      float2 h = Hbuf[((size_t)((b * 8 + c) * 512 + d)) * 64 + n];
      G.x += R[c].x * h.x - R[c].y * h.y;
      G.y += R[c].x * h.y + R[c].y * h.x;
    }
  }
  __syncthreads();
  const uint4* src = (const uint4*)tile;
  uint4* dst = (uint4*)(seedB + (size_t)d * 16384);
  for (int k = tid; k < 2048; k += 256) dst[k] = src[k];
}

// ---- K4: per-d Toeplitz + seed GEMM (MFMA), writes yraw (d,b,l) bf16 --------
// block = (d, tq): M=128 taus at t0=tq*128, N=128 (b,c), K=640 (512 u-taps + 128 seed).
// T[tau,k] = Kc[tau-k] (tau>=k else 0), Kc[j]=K[4095-j] -> T[tau,k]=KR[511-tau+k],
// KR[x]=Kbuf[d][x] for x<512 else 0. 8 shifted LDS copies give aligned b128 frags.
// P[tau,2n]=Re(W A^(511-tau)), P[tau,2n+1]=-Im(...): built in LDS via recurrence.
#define KRN 1048
__global__ __launch_bounds__(256) void k_conv(
    const ushort_t* __restrict__ u_bf, const ushort_t* __restrict__ Kbuf,
    const ushort_t* __restrict__ seedB,
    const float* __restrict__ p_ar, const float* __restrict__ p_ai,
    const float* __restrict__ p_wr, const float* __restrict__ p_wi,
    const float* __restrict__ p_dr, const float* __restrict__ p_di,
    ushort_t* __restrict__ yraw) {
  __shared__ ushort_t KRc[8][KRN];
  __shared__ ushort_t PLD[128][136];   // pad 136 for bank spread, 16B-aligned rows
  int d = blockIdx.x;
  int t0 = blockIdx.y * 128;
  int tid = threadIdx.x;

  for (int e = tid; e < 8 * KRN; e += 256) {
    int r = e / KRN, x = e - r * KRN;
    int y = x + r;
    KRc[r][x] = (y < 512) ? Kbuf[d * 512 + y] : (ushort_t)0;
  }
  {
    int n = tid & 63, mh = tid >> 6;
    int i = d * 64 + n;
    float ar = p_ar[i], ai = p_ai[i];
    float wr = p_wr[i], wi = p_wi[i];
    int mtop = mh * 32 + 31;
    f2 E = cexp(p_dr[i], p_di[i], (float)(511 - t0 - mtop));
    float zr = wr * E.x - wi * E.y;
    float zi = wr * E.y + wi * E.x;
    for (int m = mtop; m >= mh * 32; --m) {
      PLD[m][2 * n]     = f2bf(zr);
      PLD[m][2 * n + 1] = f2bf(-zi);
      float tr = zr * ar - zi * ai;   // exponent +1 as m decreases
      zi = zr * ai + zi * ar;
      zr = tr;
    }
  }
  __syncthreads();

  int wv = tid >> 6, lane = tid & 63;
  int wm = wv >> 1, wn = wv & 1;
  int lrow = lane & 15, quad = lane >> 4;
  f32x4 acc[4][4];
#pragma unroll
  for (int mt = 0; mt < 4; ++mt)
#pragma unroll
    for (int nt = 0; nt < 4; ++nt) acc[mt][nt] = (f32x4){0.f, 0.f, 0.f, 0.f};

  // Toeplitz part: k-iters 0..15 over the chunk's 512 u-taps
  for (int kt = 0; kt < 16; ++kt) {
    int kbase = kt * 32 + quad * 8;
    short8 af[4], bf[4];
#pragma unroll
    for (int mt = 0; mt < 4; ++mt) {
      int m = wm * 64 + mt * 16 + lrow;
      int idx = 511 - t0 - m + kbase;
      int r = idx & 7, st = idx - r;
      af[mt] = *(const short8*)&KRc[r][st];
    }
#pragma unroll
    for (int nt = 0; nt < 4; ++nt) {
      int col = wn * 64 + nt * 16 + lrow;
      int b = col >> 3, c = col & 7;
      bf[nt] = *(const short8*)(u_bf + (size_t)(b * 512 + d) * 4096 + c * 512 + kbase);
    }
#pragma unroll
    for (int mt = 0; mt < 4; ++mt)
#pragma unroll
      for (int nt = 0; nt < 4; ++nt)
        acc[mt][nt] = __builtin_amdgcn_mfma_f32_16x16x32_bf16(af[mt], bf[nt], acc[mt][nt], 0, 0, 0);
  }
  // Seed part: k-iters 16..19 over 128 seed rows
  for (int kt = 0; kt < 4; ++kt) {
    int k2 = kt * 32 + quad * 8;
    short8 af[4], bf[4];
#pragma unroll
    for (int mt = 0; mt < 4; ++mt)
      af[mt] = *(const short8*)&PLD[wm * 64 + mt * 16 + lrow][k2];
#pragma unroll
    for (int nt = 0; nt < 4; ++nt) {
      int col = wn * 64 + nt * 16 + lrow;
      bf[nt] = *(const short8*)(seedB + (size_t)d * 16384 + col * 128 + k2);
    }
#pragma unroll
    for (int mt = 0; mt < 4; ++mt)
#pragma unroll
      for (int nt = 0; nt < 4; ++nt)
        acc[mt][nt] = __builtin_amdgcn_mfma_f32_16x16x32_bf16(af[mt], bf[nt], acc[mt][nt], 0, 0, 0);
  }

  // epilogue: yraw[d][b][l=c*512+tau] bf16, 4 regs = 4 consecutive taus -> 8B store
#pragma unroll
  for (int mt = 0; mt < 4; ++mt) {
#pragma unroll
    for (int nt = 0; nt < 4; ++nt) {
      int col = wn * 64 + nt * 16 + lrow;
      int b = col >> 3, c = col & 7;
      int tau = t0 + wm * 64 + mt * 16 + quad * 4;
      uint_t lo = (uint_t)f2bf(acc[mt][nt][0]) | ((uint_t)f2bf(acc[mt][nt][1]) << 16);
      uint_t hi = (uint_t)f2bf(acc[mt][nt][2]) | ((uint_t)f2bf(acc[mt][nt][3]) << 16);
      uint2 vv = {lo, hi};
      *(uint2*)(yraw + (size_t)d * 65536 + b * 4096 + c * 512 + tau) = vv;
    }
  }
}

// ---- K5: transpose + D*u + exact gelu: yraw (d,b,l) -> yg (b,l,d) bf16 ------
__global__ __launch_bounds__(256) void k_tg(
    const ushort_t* __restrict__ yraw, const float* __restrict__ u,
    const float* __restrict__ Dvec, ushort_t* __restrict__ yg) {
  __shared__ ushort_t tile[64][72];   // swizzled cols, row stride 144B (16B-aligned)
  int blk = blockIdx.x;
  int b = blk >> 9, dg = (blk >> 6) & 7, lg = blk & 63;
  int d0 = dg * 64, l0 = lg * 64;
  int tid = threadIdx.x;
  int dd = tid >> 2, lc = (tid & 3) * 16;

  const ushort_t* yp = yraw + (size_t)(d0 + dd) * 65536 + b * 4096 + l0 + lc;
  const float* up = u + ((size_t)(b * 512 + d0 + dd)) * 4096 + l0 + lc;
  float Dd = Dvec[d0 + dd];
  uint4 A0 = *(const uint4*)yp;
  uint4 A1 = *(const uint4*)(yp + 8);
  uint_t w[8] = {A0.x, A0.y, A0.z, A0.w, A1.x, A1.y, A1.z, A1.w};
  float uu[16];
#pragma unroll
  for (int q = 0; q < 4; ++q) {
    float4 uv = *(const float4*)(up + q * 4);
    uu[q*4+0] = uv.x; uu[q*4+1] = uv.y; uu[q*4+2] = uv.z; uu[q*4+3] = uv.w;
  }
#pragma unroll
  for (int i2 = 0; i2 < 16; ++i2) {
    ushort_t bits = (i2 & 1) ? (ushort_t)(w[i2 >> 1] >> 16) : (ushort_t)(w[i2 >> 1] & 0xffff);
    float y = bf2f(bits) + Dd * uu[i2];
    float g = 0.5f * y * (1.0f + erff(y * 0.70710678118654752f));
    int row = lc + i2;
    int col = (dd + ((row >> 3) & 7) * 8) & 63;
    tile[row][col] = f2bf(g);
  }
  __syncthreads();
  int lr = tid >> 2, dc = (tid & 3) * 16;
  int rot = ((lr >> 3) & 7) * 8;
  int o1 = (dc + rot) & 63;
  int o2 = (dc + 8 + rot) & 63;
  uint4 v1 = *(const uint4*)&tile[lr][o1];
  uint4 v2 = *(const uint4*)&tile[lr][o2];
  ushort_t* og = yg + (size_t)b * (4096 * 512) + (size_t)(l0 + lr) * 512 + d0 + dc;
  *(uint4*)og = v1;
  *(uint4*)(og + 8) = v2;
}

// ---- 1x1 conv (512->1024) + bias + GLU + sum-over-L, fused (unchanged) ------
__global__ __launch_bounds__(256) void k_gemm(
    const ushort_t* __restrict__ wbf, const ushort_t* __restrict__ yg,
    const float* __restrict__ b_out, float* __restrict__ pooled) {
  __shared__ ushort_t lwa[64][88];
  __shared__ ushort_t lwg[64][88];
  __shared__ ushort_t ly[64][88];
  int tid = threadIdx.x;
  int mp0 = blockIdx.x * 64;
  int n0 = blockIdx.y * 64;
  int b = n0 >> 12;
  int wv = tid >> 6, lane = tid & 63;
  int mhalf = wv >> 1, nhalf = wv & 1;
  int lrow = lane & 15, quad = lane >> 4;
  f32x4 accA[2][2], accG[2][2];
#pragma unroll
  for (int mt = 0; mt < 2; ++mt)
#pragma unroll
    for (int nt = 0; nt < 2; ++nt) {
      accA[mt][nt] = (f32x4){0.f, 0.f, 0.f, 0.f};
      accG[mt][nt] = (f32x4){0.f, 0.f, 0.f, 0.f};
    }
  int srow = tid >> 2;
  int scol = (tid & 3) * 16;
  for (int kc = 0; kc < 512; kc += 64) {
    const uint4* pa = (const uint4*)(wbf + (size_t)(mp0 + srow) * 512 + kc + scol);
    const uint4* pg = (const uint4*)(wbf + (size_t)(512 + mp0 + srow) * 512 + kc + scol);
    const uint4* py = (const uint4*)(yg + (size_t)(n0 + srow) * 512 + kc + scol);
    uint4 va0 = pa[0], va1 = pa[1];
    uint4 vg0 = pg[0], vg1 = pg[1];
    uint4 vy0 = py[0], vy1 = py[1];
    *(uint4*)&lwa[srow][scol] = va0; *(uint4*)&lwa[srow][scol + 8] = va1;
    *(uint4*)&lwg[srow][scol] = vg0; *(uint4*)&lwg[srow][scol + 8] = vg1;
    *(uint4*)&ly[srow][scol] = vy0;  *(uint4*)&ly[srow][scol + 8] = vy1;
    __syncthreads();
#pragma unroll
    for (int kb = 0; kb < 2; ++kb) {
      int ko = kb * 32 + quad * 8;
      short8 bfv[2], af[2], gf[2];
#pragma unroll
      for (int nt = 0; nt < 2; ++nt)
        bfv[nt] = *(const short8*)&ly[nhalf * 32 + nt * 16 + lrow][ko];
#pragma unroll
      for (int mt = 0; mt < 2; ++mt) {
        af[mt] = *(const short8*)&lwa[mhalf * 32 + mt * 16 + lrow][ko];
        gf[mt] = *(const short8*)&lwg[mhalf * 32 + mt * 16 + lrow][ko];
      }
#pragma unroll
      for (int mt = 0; mt < 2; ++mt)
#pragma unroll
        for (int nt = 0; nt < 2; ++nt) {
          accA[mt][nt] = __builtin_amdgcn_mfma_f32_16x16x32_bf16(af[mt], bfv[nt], accA[mt][nt], 0, 0, 0);
          accG[mt][nt] = __builtin_amdgcn_mfma_f32_16x16x32_bf16(gf[mt], bfv[nt], accG[mt][nt], 0, 0, 0);
        }
    }
    __syncthreads();
  }
#pragma unroll
  for (int mt = 0; mt < 2; ++mt) {
#pragma unroll
    for (int reg = 0; reg < 4; ++reg) {
      int olocal = mhalf * 32 + mt * 16 + quad * 4 + reg;
      float ba = b_out[mp0 + olocal];
      float bg = b_out[512 + mp0 + olocal];
      float h = 0.f;
#pragma unroll
      for (int nt = 0; nt < 2; ++nt) {
        float a = accA[mt][nt][reg] + ba;
        float gv = accG[mt][nt][reg] + bg;
        h += a / (1.0f + __expf(-gv));
      }
#pragma unroll
      for (int off = 1; off < 16; off <<= 1) h += __shfl_xor(h, off, 16);
      if (lrow == 0) atomicAdd(&pooled[b * 512 + mp0 + olocal], h);
    }
  }
}

// ---- decoder ----------------------------------------------------------------
__global__ void k_final(const float* __restrict__ pooled, const float* __restrict__ W_dec,
                        const float* __restrict__ b_dec, float* __restrict__ out) {
  int b = blockIdx.x;
  int lane = threadIdx.x;
  float s = 0.f;
#pragma unroll
  for (int j = 0; j < 8; ++j) s += pooled[b * 512 + lane + 64 * j] * W_dec[lane + 64 * j];
#pragma unroll
  for (int off = 1; off < 64; off <<= 1) s += __shfl_xor(s, off, 64);
  if (lane == 0) out[b] = s * (1.0f / 4096.0f) + b_dec[0];
}

extern "C" void kernel_launch(void* const* d_in, const int* in_sizes, int n_in,
                              void* d_out, int out_size, void* d_ws, size_t ws_size,
                              hipStream_t stream) {
  const float* u          = (const float*)d_in[0];
  const float* log_dt     = (const float*)d_in[1];
  const float* log_A_real = (const float*)d_in[2];
  const float* A_imag     = (const float*)d_in[3];
  const float* B_re       = (const float*)d_in[4];
  const float* B_im       = (const float*)d_in[5];
  const float* C_re       = (const float*)d_in[6];
  const float* C_im       = (const float*)d_in[7];
  const float* Dv         = (const float*)d_in[8];
  const float* W_out      = (const float*)d_in[9];
  const float* b_out      = (const float*)d_in[10];
  const float* W_dec      = (const float*)d_in[11];
  const float* b_dec      = (const float*)d_in[12];

  float* ws = (float*)d_ws;
  float* p_ar = ws;
  float* p_ai = ws + 32768;
  float* p_wr = ws + 65536;
  float* p_wi = ws + 98304;
  float* p_dr = ws + 131072;
  float* p_di = ws + 163840;
  float* p_lr = ws + 196608;
  float* p_li = ws + 229376;
  float* pooled = (float*)((char*)d_ws + UOFF_POOLED);
  ushort_t* wbf   = (ushort_t*)((char*)d_ws + UOFF_WBF);
  ushort_t* u_bf  = (ushort_t*)((char*)d_ws + UOFF_UBF);
  ushort_t* yg    = (ushort_t*)((char*)d_ws + UOFF_UBF);    // alias: reused after k_conv
  ushort_t* yraw  = (ushort_t*)((char*)d_ws + UOFF_YRAW);
  float2*   Hbuf  = (float2*)((char*)d_ws + UOFF_YRAW);     // alias: dead before k_conv writes
  ushort_t* seedB = (ushort_t*)((char*)d_ws + UOFF_SEEDB);
  ushort_t* Kbuf  = (ushort_t*)((char*)d_ws + UOFF_KBUF);

  hipMemsetAsync(pooled, 0, 16 * 512 * sizeof(float), stream);
  k_params<<<128, 256, 0, stream>>>(log_dt, log_A_real, A_imag, B_re, B_im, C_re, C_im,
                                    p_ar, p_ai, p_wr, p_wi, p_dr, p_di, p_lr, p_li);
  k_wcvt<<<2048, 256, 0, stream>>>(W_out, wbf, 1024 * 512);
  k_chunk<<<2048, 256, 0, stream>>>(u, p_ar, p_ai, Hbuf, u_bf);
  k_kc<<<512, 64, 0, stream>>>(p_ar, p_ai, p_wr, p_wi, p_dr, p_di, Kbuf);
  k_seedpack<<<512, 256, 0, stream>>>(p_dr, p_di, Hbuf, seedB);
  k_conv<<<dim3(512, 4), 256, 0, stream>>>(u_bf, Kbuf, seedB,
                                           p_ar, p_ai, p_wr, p_wi, p_dr, p_di, yraw);
  k_tg<<<8192, 256, 0, stream>>>(yraw, u, Dv, yg);
  k_gemm<<<dim3(8, 1024), 256, 0, stream>>>(wbf, yg, b_out, pooled);
  k_final<<<16, 64, 0, stream>>>(pooled, W_dec, b_dec, (float*)d_out);
}

// Round 6
// 620.284 us; speedup vs baseline: 4.2278x; 1.3499x over previous
//
#include <hip/hip_runtime.h>

// MiniS4D: B=16, D=512, N=64 states, L=4096, C=8 chunks of S=512.
// Pipeline: k_params -> k_wcvt -> k_ucvt (u->bf16) -> k_hgemm (Vandermonde MFMA -> H)
//           -> k_kc (kernel tail) -> k_seedpack -> k_conv (Toeplitz+seed MFMA, yraw (d,b,l))
//           -> k_tg (transpose + D*u + gelu -> yg (b,l,d)) -> k_gemm (GLU) -> k_final
// ws byte layout (153.6 MB, same as R5):
//   [0)          params: p_ar,p_ai,p_wr,p_wi,p_dr,p_di,p_lr,p_li (8 x 131072)
//   [1048576)    pooled 32KB
//   [1081344)    wbf 1MB
//   [2129920)    UBF  u_bf bf16 67.1MB   (ALIAS: yg reuses this region after k_conv)
//   [69238784)   YRAW bf16 67.1MB        (ALIAS: Hbuf float2 33.55MB in first half)
//   [136347648)  seedB bf16 16.8MB
//   [153124864)  Kbuf bf16 0.52MB  -> end 153649152

#define UOFF_POOLED 1048576
#define UOFF_WBF    1081344
#define UOFF_UBF    2129920
#define UOFF_YRAW   69238784
#define UOFF_SEEDB  136347648
#define UOFF_KBUF   153124864

typedef __attribute__((ext_vector_type(8))) short short8;
typedef __attribute__((ext_vector_type(4))) float f32x4;
typedef __attribute__((ext_vector_type(2))) float f2;
typedef unsigned short ushort_t;
typedef unsigned int uint_t;

__device__ __forceinline__ ushort_t f2bf(float f) {
  uint_t u = __float_as_uint(f);
  u = (u + 0x7FFF + ((u >> 16) & 1)) >> 16;  // RNE
  return (ushort_t)u;
}
__device__ __forceinline__ float bf2f(ushort_t v) {
  return __uint_as_float(((uint_t)v) << 16);
}

// exp(dr*t) * cis(di*t)
__device__ __forceinline__ f2 cexp(float dr, float di, float t) {
  float e = expf(dr * t);
  float ph = di * t;
  return (f2){e * cosf(ph), e * sinf(ph)};
}

// ---- derived SSM params ----------------------------------------------------
__global__ void k_params(const float* __restrict__ log_dt,
                         const float* __restrict__ log_A_real,
                         const float* __restrict__ A_imag,
                         const float* __restrict__ B_re, const float* __restrict__ B_im,
                         const float* __restrict__ C_re, const float* __restrict__ C_im,
                         float* __restrict__ p_ar, float* __restrict__ p_ai,
                         float* __restrict__ p_wr, float* __restrict__ p_wi,
                         float* __restrict__ p_dr, float* __restrict__ p_di,
                         float* __restrict__ p_lr, float* __restrict__ p_li) {
  int i = blockIdx.x * blockDim.x + threadIdx.x;   // 0..32767, d = i>>6
  int d = i >> 6;
  float dt  = expf(log_dt[d]);
  float Are = -expf(log_A_real[i]);
  float Aim = A_imag[i];
  float dre = dt * Are, dim = dt * Aim;
  float em  = expf(dre);
  float abr = em * cosf(dim);
  float abi = em * sinf(dim);
  float nr = abr - 1.0f, ni = abi;
  float inv = 1.0f / (Are * Are + Aim * Aim);
  float br = (nr * Are + ni * Aim) * inv;
  float bi = (ni * Are - nr * Aim) * inv;
  float Br = B_re[i], Bi = B_im[i];
  float b2r = br * Br - bi * Bi;
  float b2i = br * Bi + bi * Br;
  float Cr = C_re[i], Ci = C_im[i];
  p_ar[i] = abr; p_ai[i] = abi;
  p_wr[i] = Cr * b2r - Ci * b2i;
  p_wi[i] = Cr * b2i + Ci * b2r;
  p_dr[i] = dre; p_di[i] = dim;
  float eL = expf(dre * 4096.0f);
  float phL = dim * 4096.0f;
  p_lr[i] = eL * cosf(phL);
  p_li[i] = eL * sinf(phL);
}

// ---- W_out fp32 -> bf16 -----------------------------------------------------
__global__ void k_wcvt(const float* __restrict__ w, ushort_t* __restrict__ wb, int n) {
  int i = blockIdx.x * blockDim.x + threadIdx.x;
  if (i < n) wb[i] = f2bf(w[i]);
}

// ---- u fp32 -> bf16 (8 elems/thread) ---------------------------------------
__global__ __launch_bounds__(256) void k_ucvt(const float* __restrict__ u,
                                              ushort_t* __restrict__ u_bf) {
  size_t i = (size_t)blockIdx.x * 256 + threadIdx.x;   // per 8 elems
  const float4* p = (const float4*)u + 2 * i;
  float4 a = p[0], b = p[1];
  uint4 v;
  v.x = (uint_t)f2bf(a.x) | ((uint_t)f2bf(a.y) << 16);
  v.y = (uint_t)f2bf(a.z) | ((uint_t)f2bf(a.w) << 16);
  v.z = (uint_t)f2bf(b.x) | ((uint_t)f2bf(b.y) << 16);
  v.w = (uint_t)f2bf(b.z) | ((uint_t)f2bf(b.w) << 16);
  ((uint4*)u_bf)[i] = v;
}

// ---- K1: H sums via MFMA ---------------------------------------------------
// One block per d. M=128 rows (m=2n+p: Re/Im of A_n^t), K=512 (t), N=128 cols (b*8+c).
// V built in LDS per 128-wide K-tile via per-thread complex recurrence.
// XOR granule swizzle (granule = 8 elems = 16B): phys_g = g ^ (m & 7).
__global__ __launch_bounds__(256) void k_hgemm(
    const ushort_t* __restrict__ u_bf,
    const float* __restrict__ p_ar, const float* __restrict__ p_ai,
    const float* __restrict__ p_dr, const float* __restrict__ p_di,
    float2* __restrict__ Hbuf) {
  __shared__ ushort_t VLD[128][128];
  int d = blockIdx.x;
  int tid = threadIdx.x;
  int wv = tid >> 6, lane = tid & 63;
  int wm = wv >> 1, wn = wv & 1;
  int lrow = lane & 15, quad = lane >> 4;

  // build-role mapping: thread -> (row m, chalf of 64 t's)
  int m = tid & 127, chalf = tid >> 7;
  int nn = m >> 1, pp = m & 1;
  float ar = p_ar[d * 64 + nn], ai = p_ai[d * 64 + nn];
  float dr = p_dr[d * 64 + nn], di = p_di[d * 64 + nn];

  f32x4 acc[4][4];
#pragma unroll
  for (int mt = 0; mt < 4; ++mt)
#pragma unroll
    for (int nt = 0; nt < 4; ++nt) acc[mt][nt] = (f32x4){0.f, 0.f, 0.f, 0.f};

  for (int kt = 0; kt < 4; ++kt) {
    f2 z = cexp(dr, di, (float)(kt * 128 + chalf * 64));
#pragma unroll
    for (int g8 = 0; g8 < 8; ++g8) {
      ushort_t vals[8];
#pragma unroll
      for (int e = 0; e < 8; ++e) {
        vals[e] = f2bf(pp ? z.y : z.x);
        float zr = z.x * ar - z.y * ai;
        z.y = z.x * ai + z.y * ar;
        z.x = zr;
      }
      int g = (chalf * 64 + g8 * 8) >> 3;
      int gph = g ^ (m & 7);
      uint4 pk;
      pk.x = (uint_t)vals[0] | ((uint_t)vals[1] << 16);
      pk.y = (uint_t)vals[2] | ((uint_t)vals[3] << 16);
      pk.z = (uint_t)vals[4] | ((uint_t)vals[5] << 16);
      pk.w = (uint_t)vals[6] | ((uint_t)vals[7] << 16);
      *(uint4*)&VLD[m][gph << 3] = pk;
    }
    __syncthreads();
#pragma unroll
    for (int kb = 0; kb < 4; ++kb) {
      int kbase = kb * 32 + quad * 8;
      short8 af[4], bf[4];
#pragma unroll
      for (int mt = 0; mt < 4; ++mt) {
        int mrow = wm * 64 + mt * 16 + lrow;
        int gph = (kbase >> 3) ^ (mrow & 7);
        af[mt] = *(const short8*)&VLD[mrow][gph << 3];
      }
#pragma unroll
      for (int nt = 0; nt < 4; ++nt) {
        int col = wn * 64 + nt * 16 + lrow;
        int b = col >> 3, c = col & 7;
        bf[nt] = *(const short8*)(u_bf + (size_t)(b * 512 + d) * 4096 + c * 512 + kt * 128 + kbase);
      }
#pragma unroll
      for (int mt = 0; mt < 4; ++mt)
#pragma unroll
        for (int nt = 0; nt < 4; ++nt)
          acc[mt][nt] = __builtin_amdgcn_mfma_f32_16x16x32_bf16(af[mt], bf[nt], acc[mt][nt], 0, 0, 0);
    }
    __syncthreads();
  }
  // epilogue: rows m0..m0+3 = (Re,Im,Re,Im) of states n0,n0+1 -> one float4
#pragma unroll
  for (int mt = 0; mt < 4; ++mt) {
#pragma unroll
    for (int nt = 0; nt < 4; ++nt) {
      int col = wn * 64 + nt * 16 + lrow;
      int b = col >> 3, c = col & 7;
      int m0 = wm * 64 + mt * 16 + quad * 4;
      int n0 = m0 >> 1;
      float4 v = {acc[mt][nt][0], acc[mt][nt][1], acc[mt][nt][2], acc[mt][nt][3]};
      *(float4*)((float*)(Hbuf + ((size_t)((b * 8 + c) * 512 + d)) * 64 + n0)) = v;
    }
  }
}

// ---- K2: kernel tail Kbuf[d][x] = K[3584+x] = Re sum_n W_n A^(3584+x), bf16 --
__global__ __launch_bounds__(64) void k_kc(
    const float* __restrict__ p_ar, const float* __restrict__ p_ai,
    const float* __restrict__ p_wr, const float* __restrict__ p_wi,
    const float* __restrict__ p_dr, const float* __restrict__ p_di,
    ushort_t* __restrict__ Kbuf) {
  int d = blockIdx.x;
  int n = threadIdx.x;
  int i = d * 64 + n;
  float ar = p_ar[i], ai = p_ai[i];
  float wr = p_wr[i], wi = p_wi[i];
  f2 e = cexp(p_dr[i], p_di[i], 3584.0f);
  float zr = wr * e.x - wi * e.y;
  float zi = wr * e.y + wi * e.x;
  for (int x = 0; x < 512; ++x) {
    float s = zr;
#pragma unroll
    for (int off = 1; off < 64; off <<= 1) s += __shfl_xor(s, off, 64);
    if (n == 0) Kbuf[d * 512 + x] = f2bf(s);
    float tr = zr * ar - zi * ai;
    zi = zr * ai + zi * ar;
    zr = tr;
  }
}

// ---- K3: seeds. s[c] = A^((7-c)S) * F[cS-1], F excl own chunk. --------------
__global__ __launch_bounds__(256) void k_seedpack(
    const float* __restrict__ p_dr, const float* __restrict__ p_di,
    const float2* __restrict__ Hbuf, ushort_t* __restrict__ seedB) {
  __shared__ ushort_t tile[128 * 128];
  int d = blockIdx.x;
  int tid = threadIdx.x;
  int n = tid >> 2;      // 0..63
  int bq = tid & 3;
  float dr = p_dr[d * 64 + n], di = p_di[d * 64 + n];
  f2 AS = cexp(dr, di, 512.0f);
  f2 R[8];
  R[0] = (f2){1.f, 0.f};
#pragma unroll
  for (int c = 1; c < 8; ++c)
    R[c] = (f2){R[c-1].x * AS.x - R[c-1].y * AS.y, R[c-1].x * AS.y + R[c-1].y * AS.x};
  for (int bb = 0; bb < 4; ++bb) {
    int b = bq * 4 + bb;
    f2 G = {0.f, 0.f};
#pragma unroll
    for (int c = 0; c < 8; ++c) {
      f2 T = R[7 - c];
      float sr = T.x * G.x - T.y * G.y;
      float si = T.x * G.y + T.y * G.x;
      int col = b * 8 + c;
      tile[col * 128 + 2 * n]     = f2bf(sr);
      tile[col * 128 + 2 * n + 1] = f2bf(si);
      float2 h = Hbuf[((size_t)((b * 8 + c) * 512 + d)) * 64 + n];
      G.x += R[c].x * h.x - R[c].y * h.y;
      G.y += R[c].x * h.y + R[c].y * h.x;
    }
  }
  __syncthreads();
  const uint4* src = (const uint4*)tile;
  uint4* dst = (uint4*)(seedB + (size_t)d * 16384);
  for (int k = tid; k < 2048; k += 256) dst[k] = src[k];
}

// ---- K4: per-d Toeplitz + seed GEMM (MFMA), writes yraw (d,b,l) bf16 --------
#define KRN 1048
__global__ __launch_bounds__(256) void k_conv(
    const ushort_t* __restrict__ u_bf, const ushort_t* __restrict__ Kbuf,
    const ushort_t* __restrict__ seedB,
    const float* __restrict__ p_ar, const float* __restrict__ p_ai,
    const float* __restrict__ p_wr, const float* __restrict__ p_wi,
    const float* __restrict__ p_dr, const float* __restrict__ p_di,
    ushort_t* __restrict__ yraw) {
  __shared__ ushort_t KRc[8][KRN];
  __shared__ ushort_t PLD[128][136];
  int d = blockIdx.x;
  int t0 = blockIdx.y * 128;
  int tid = threadIdx.x;

  for (int e = tid; e < 8 * KRN; e += 256) {
    int r = e / KRN, x = e - r * KRN;
    int y = x + r;
    KRc[r][x] = (y < 512) ? Kbuf[d * 512 + y] : (ushort_t)0;
  }
  {
    int n = tid & 63, mh = tid >> 6;
    int i = d * 64 + n;
    float ar = p_ar[i], ai = p_ai[i];
    float wr = p_wr[i], wi = p_wi[i];
    int mtop = mh * 32 + 31;
    f2 E = cexp(p_dr[i], p_di[i], (float)(511 - t0 - mtop));
    float zr = wr * E.x - wi * E.y;
    float zi = wr * E.y + wi * E.x;
    for (int m = mtop; m >= mh * 32; --m) {
      PLD[m][2 * n]     = f2bf(zr);
      PLD[m][2 * n + 1] = f2bf(-zi);
      float tr = zr * ar - zi * ai;
      zi = zr * ai + zi * ar;
      zr = tr;
    }
  }
  __syncthreads();

  int wv = tid >> 6, lane = tid & 63;
  int wm = wv >> 1, wn = wv & 1;
  int lrow = lane & 15, quad = lane >> 4;
  f32x4 acc[4][4];
#pragma unroll
  for (int mt = 0; mt < 4; ++mt)
#pragma unroll
    for (int nt = 0; nt < 4; ++nt) acc[mt][nt] = (f32x4){0.f, 0.f, 0.f, 0.f};

  for (int kt = 0; kt < 16; ++kt) {
    int kbase = kt * 32 + quad * 8;
    short8 af[4], bf[4];
#pragma unroll
    for (int mt = 0; mt < 4; ++mt) {
      int mr = wm * 64 + mt * 16 + lrow;
      int idx = 511 - t0 - mr + kbase;
      int r = idx & 7, st = idx - r;
      af[mt] = *(const short8*)&KRc[r][st];
    }
#pragma unroll
    for (int nt = 0; nt < 4; ++nt) {
      int col = wn * 64 + nt * 16 + lrow;
      int b = col >> 3, c = col & 7;
      bf[nt] = *(const short8*)(u_bf + (size_t)(b * 512 + d) * 4096 + c * 512 + kbase);
    }
#pragma unroll
    for (int mt = 0; mt < 4; ++mt)
#pragma unroll
      for (int nt = 0; nt < 4; ++nt)
        acc[mt][nt] = __builtin_amdgcn_mfma_f32_16x16x32_bf16(af[mt], bf[nt], acc[mt][nt], 0, 0, 0);
  }
  for (int kt = 0; kt < 4; ++kt) {
    int k2 = kt * 32 + quad * 8;
    short8 af[4], bf[4];
#pragma unroll
    for (int mt = 0; mt < 4; ++mt)
      af[mt] = *(const short8*)&PLD[wm * 64 + mt * 16 + lrow][k2];
#pragma unroll
    for (int nt = 0; nt < 4; ++nt) {
      int col = wn * 64 + nt * 16 + lrow;
      bf[nt] = *(const short8*)(seedB + (size_t)d * 16384 + col * 128 + k2);
    }
#pragma unroll
    for (int mt = 0; mt < 4; ++mt)
#pragma unroll
      for (int nt = 0; nt < 4; ++nt)
        acc[mt][nt] = __builtin_amdgcn_mfma_f32_16x16x32_bf16(af[mt], bf[nt], acc[mt][nt], 0, 0, 0);
  }

#pragma unroll
  for (int mt = 0; mt < 4; ++mt) {
#pragma unroll
    for (int nt = 0; nt < 4; ++nt) {
      int col = wn * 64 + nt * 16 + lrow;
      int b = col >> 3, c = col & 7;
      int tau = t0 + wm * 64 + mt * 16 + quad * 4;
      uint_t lo = (uint_t)f2bf(acc[mt][nt][0]) | ((uint_t)f2bf(acc[mt][nt][1]) << 16);
      uint_t hi = (uint_t)f2bf(acc[mt][nt][2]) | ((uint_t)f2bf(acc[mt][nt][3]) << 16);
      uint2 vv = {lo, hi};
      *(uint2*)(yraw + (size_t)d * 65536 + b * 4096 + c * 512 + tau) = vv;
    }
  }
}

// ---- K5: transpose + D*u + exact gelu: yraw (d,b,l) -> yg (b,l,d) bf16 ------
__global__ __launch_bounds__(256) void k_tg(
    const ushort_t* __restrict__ yraw, const float* __restrict__ u,
    const float* __restrict__ Dvec, ushort_t* __restrict__ yg) {
  __shared__ ushort_t tile[64][72];
  int blk = blockIdx.x;
  int b = blk >> 9, dg = (blk >> 6) & 7, lg = blk & 63;
  int d0 = dg * 64, l0 = lg * 64;
  int tid = threadIdx.x;
  int dd = tid >> 2, lc = (tid & 3) * 16;

  const ushort_t* yp = yraw + (size_t)(d0 + dd) * 65536 + b * 4096 + l0 + lc;
  const float* up = u + ((size_t)(b * 512 + d0 + dd)) * 4096 + l0 + lc;
  float Dd = Dvec[d0 + dd];
  uint4 A0 = *(const uint4*)yp;
  uint4 A1 = *(const uint4*)(yp + 8);
  uint_t w[8] = {A0.x, A0.y, A0.z, A0.w, A1.x, A1.y, A1.z, A1.w};
  float uu[16];
#pragma unroll
  for (int q = 0; q < 4; ++q) {
    float4 uv = *(const float4*)(up + q * 4);
    uu[q*4+0] = uv.x; uu[q*4+1] = uv.y; uu[q*4+2] = uv.z; uu[q*4+3] = uv.w;
  }
#pragma unroll
  for (int i2 = 0; i2 < 16; ++i2) {
    ushort_t bits = (i2 & 1) ? (ushort_t)(w[i2 >> 1] >> 16) : (ushort_t)(w[i2 >> 1] & 0xffff);
    float y = bf2f(bits) + Dd * uu[i2];
    float g = 0.5f * y * (1.0f + erff(y * 0.70710678118654752f));
    int row = lc + i2;
    int col = (dd + ((row >> 3) & 7) * 8) & 63;
    tile[row][col] = f2bf(g);
  }
  __syncthreads();
  int lr = tid >> 2, dc = (tid & 3) * 16;
  int rot = ((lr >> 3) & 7) * 8;
  int o1 = (dc + rot) & 63;
  int o2 = (dc + 8 + rot) & 63;
  uint4 v1 = *(const uint4*)&tile[lr][o1];
  uint4 v2 = *(const uint4*)&tile[lr][o2];
  ushort_t* og = yg + (size_t)b * (4096 * 512) + (size_t)(l0 + lr) * 512 + d0 + dc;
  *(uint4*)og = v1;
  *(uint4*)(og + 8) = v2;
}

// ---- 1x1 conv (512->1024) + bias + GLU + sum-over-L, fused; N=128 tile ------
__global__ __launch_bounds__(256) void k_gemm(
    const ushort_t* __restrict__ wbf, const ushort_t* __restrict__ yg,
    const float* __restrict__ b_out, float* __restrict__ pooled) {
  __shared__ ushort_t lwa[64][72];
  __shared__ ushort_t lwg[64][72];
  __shared__ ushort_t ly[128][72];
  int tid = threadIdx.x;
  int mp0 = blockIdx.x * 64;
  int n0 = blockIdx.y * 128;
  int b = n0 >> 12;
  int wv = tid >> 6, lane = tid & 63;
  int mh = wv >> 1, nh = wv & 1;
  int lrow = lane & 15, quad = lane >> 4;
  f32x4 accA[2][4], accG[2][4];
#pragma unroll
  for (int mt = 0; mt < 2; ++mt)
#pragma unroll
    for (int nt = 0; nt < 4; ++nt) {
      accA[mt][nt] = (f32x4){0.f, 0.f, 0.f, 0.f};
      accG[mt][nt] = (f32x4){0.f, 0.f, 0.f, 0.f};
    }
  int srow = tid >> 2, scol = (tid & 3) * 16;
  int srow2 = tid >> 1, scol2 = (tid & 1) * 32;
  for (int kc = 0; kc < 512; kc += 64) {
    const uint4* pa = (const uint4*)(wbf + (size_t)(mp0 + srow) * 512 + kc + scol);
    const uint4* pg = (const uint4*)(wbf + (size_t)(512 + mp0 + srow) * 512 + kc + scol);
    const uint4* py = (const uint4*)(yg + (size_t)(n0 + srow2) * 512 + kc + scol2);
    uint4 va0 = pa[0], va1 = pa[1];
    uint4 vg0 = pg[0], vg1 = pg[1];
    uint4 vy0 = py[0], vy1 = py[1], vy2 = py[2], vy3 = py[3];
    *(uint4*)&lwa[srow][scol] = va0; *(uint4*)&lwa[srow][scol + 8] = va1;
    *(uint4*)&lwg[srow][scol] = vg0; *(uint4*)&lwg[srow][scol + 8] = vg1;
    *(uint4*)&ly[srow2][scol2] = vy0;      *(uint4*)&ly[srow2][scol2 + 8] = vy1;
    *(uint4*)&ly[srow2][scol2 + 16] = vy2; *(uint4*)&ly[srow2][scol2 + 24] = vy3;
    __syncthreads();
#pragma unroll
    for (int kb = 0; kb < 2; ++kb) {
      int ko = kb * 32 + quad * 8;
      short8 bfv[4], af[2], gf[2];
#pragma unroll
      for (int nt = 0; nt < 4; ++nt)
        bfv[nt] = *(const short8*)&ly[nh * 64 + nt * 16 + lrow][ko];
#pragma unroll
      for (int mt = 0; mt < 2; ++mt) {
        af[mt] = *(const short8*)&lwa[mh * 32 + mt * 16 + lrow][ko];
        gf[mt] = *(const short8*)&lwg[mh * 32 + mt * 16 + lrow][ko];
      }
#pragma unroll
      for (int mt = 0; mt < 2; ++mt)
#pragma unroll
        for (int nt = 0; nt < 4; ++nt) {
          accA[mt][nt] = __builtin_amdgcn_mfma_f32_16x16x32_bf16(af[mt], bfv[nt], accA[mt][nt], 0, 0, 0);
          accG[mt][nt] = __builtin_amdgcn_mfma_f32_16x16x32_bf16(gf[mt], bfv[nt], accG[mt][nt], 0, 0, 0);
        }
    }
    __syncthreads();
  }
#pragma unroll
  for (int mt = 0; mt < 2; ++mt) {
#pragma unroll
    for (int reg = 0; reg < 4; ++reg) {
      int olocal = mh * 32 + mt * 16 + quad * 4 + reg;
      float ba = b_out[mp0 + olocal];
      float bg = b_out[512 + mp0 + olocal];
      float h = 0.f;
#pragma unroll
      for (int nt = 0; nt < 4; ++nt) {
        float a = accA[mt][nt][reg] + ba;
        float gv = accG[mt][nt][reg] + bg;
        h += a / (1.0f + __expf(-gv));
      }
#pragma unroll
      for (int off = 1; off < 16; off <<= 1) h += __shfl_xor(h, off, 16);
      if (lrow == 0) atomicAdd(&pooled[b * 512 + mp0 + olocal], h);
    }
  }
}

// ---- decoder ----------------------------------------------------------------
__global__ void k_final(const float* __restrict__ pooled, const float* __restrict__ W_dec,
                        const float* __restrict__ b_dec, float* __restrict__ out) {
  int b = blockIdx.x;
  int lane = threadIdx.x;
  float s = 0.f;
#pragma unroll
  for (int j = 0; j < 8; ++j) s += pooled[b * 512 + lane + 64 * j] * W_dec[lane + 64 * j];
#pragma unroll
  for (int off = 1; off < 64; off <<= 1) s += __shfl_xor(s, off, 64);
  if (lane == 0) out[b] = s * (1.0f / 4096.0f) + b_dec[0];
}

extern "C" void kernel_launch(void* const* d_in, const int* in_sizes, int n_in,
                              void* d_out, int out_size, void* d_ws, size_t ws_size,
                              hipStream_t stream) {
  const float* u          = (const float*)d_in[0];
  const float* log_dt     = (const float*)d_in[1];
  const float* log_A_real = (const float*)d_in[2];
  const float* A_imag     = (const float*)d_in[3];
  const float* B_re       = (const float*)d_in[4];
  const float* B_im       = (const float*)d_in[5];
  const float* C_re       = (const float*)d_in[6];
  const float* C_im       = (const float*)d_in[7];
  const float* Dv         = (const float*)d_in[8];
  const float* W_out      = (const float*)d_in[9];
  const float* b_out      = (const float*)d_in[10];
  const float* W_dec      = (const float*)d_in[11];
  const float* b_dec      = (const float*)d_in[12];

  float* ws = (float*)d_ws;
  float* p_ar = ws;
  float* p_ai = ws + 32768;
  float* p_wr = ws + 65536;
  float* p_wi = ws + 98304;
  float* p_dr = ws + 131072;
  float* p_di = ws + 163840;
  float* p_lr = ws + 196608;
  float* p_li = ws + 229376;
  float* pooled = (float*)((char*)d_ws + UOFF_POOLED);
  ushort_t* wbf   = (ushort_t*)((char*)d_ws + UOFF_WBF);
  ushort_t* u_bf  = (ushort_t*)((char*)d_ws + UOFF_UBF);
  ushort_t* yg    = (ushort_t*)((char*)d_ws + UOFF_UBF);    // alias: reused after k_conv
  ushort_t* yraw  = (ushort_t*)((char*)d_ws + UOFF_YRAW);
  float2*   Hbuf  = (float2*)((char*)d_ws + UOFF_YRAW);     // alias: dead before k_conv writes
  ushort_t* seedB = (ushort_t*)((char*)d_ws + UOFF_SEEDB);
  ushort_t* Kbuf  = (ushort_t*)((char*)d_ws + UOFF_KBUF);

  hipMemsetAsync(pooled, 0, 16 * 512 * sizeof(float), stream);
  k_params<<<128, 256, 0, stream>>>(log_dt, log_A_real, A_imag, B_re, B_im, C_re, C_im,
                                    p_ar, p_ai, p_wr, p_wi, p_dr, p_di, p_lr, p_li);
  k_wcvt<<<2048, 256, 0, stream>>>(W_out, wbf, 1024 * 512);
  k_ucvt<<<16384, 256, 0, stream>>>(u, u_bf);
  k_hgemm<<<512, 256, 0, stream>>>(u_bf, p_ar, p_ai, p_dr, p_di, Hbuf);
  k_kc<<<512, 64, 0, stream>>>(p_ar, p_ai, p_wr, p_wi, p_dr, p_di, Kbuf);
  k_seedpack<<<512, 256, 0, stream>>>(p_dr, p_di, Hbuf, seedB);
  k_conv<<<dim3(512, 4), 256, 0, stream>>>(u_bf, Kbuf, seedB,
                                           p_ar, p_ai, p_wr, p_wi, p_dr, p_di, yraw);
  k_tg<<<8192, 256, 0, stream>>>(yraw, u, Dv, yg);
  k_gemm<<<dim3(8, 512), 256, 0, stream>>>(wbf, yg, b_out, pooled);
  k_final<<<16, 64, 0, stream>>>(pooled, W_dec, b_dec, (float*)d_out);
}

// Round 7
// 599.894 us; speedup vs baseline: 4.3715x; 1.0340x over previous
//
#include <hip/hip_runtime.h>

// MiniS4D: B=16, D=512, N=64 states, L=4096, C=8 chunks of S=512.
// Pipeline: k_params -> k_wcvt -> k_ucvt (u->bf16) -> k_hgemm (Vandermonde MFMA -> H)
//           -> k_kc (kernel tail, D on diagonal) -> k_seedpack -> k_conv (Toeplitz+seed MFMA)
//           -> k_tg (gelu + transpose -> yg (b,l,d)) -> k_gemm (GLU) -> k_final
// ws byte layout (153.6 MB):
//   [0)          params: p_ar,p_ai,p_wr,p_wi,p_dr,p_di,p_lr,p_li (8 x 131072)
//   [1048576)    pooled 32KB
//   [1081344)    wbf 1MB
//   [2129920)    UBF  u_bf bf16 67.1MB   (ALIAS: yg reuses this region after k_conv)
//   [69238784)   YRAW bf16 67.1MB        (ALIAS: Hbuf float2 33.55MB in first half)
//   [136347648)  seedB bf16 16.8MB
//   [153124864)  Kbuf bf16 0.52MB  -> end 153649152

#define UOFF_POOLED 1048576
#define UOFF_WBF    1081344
#define UOFF_UBF    2129920
#define UOFF_YRAW   69238784
#define UOFF_SEEDB  136347648
#define UOFF_KBUF   153124864

typedef __attribute__((ext_vector_type(8))) short short8;
typedef __attribute__((ext_vector_type(4))) float f32x4;
typedef __attribute__((ext_vector_type(2))) float f2;
typedef unsigned short ushort_t;
typedef unsigned int uint_t;

__device__ __forceinline__ ushort_t f2bf(float f) {
  uint_t u = __float_as_uint(f);
  u = (u + 0x7FFF + ((u >> 16) & 1)) >> 16;  // RNE
  return (ushort_t)u;
}
__device__ __forceinline__ float bf2f(ushort_t v) {
  return __uint_as_float(((uint_t)v) << 16);
}

// exp(dr*t) * cis(di*t)
__device__ __forceinline__ f2 cexp(float dr, float di, float t) {
  float e = expf(dr * t);
  float ph = di * t;
  return (f2){e * cosf(ph), e * sinf(ph)};
}

// ---- derived SSM params ----------------------------------------------------
__global__ void k_params(const float* __restrict__ log_dt,
                         const float* __restrict__ log_A_real,
                         const float* __restrict__ A_imag,
                         const float* __restrict__ B_re, const float* __restrict__ B_im,
                         const float* __restrict__ C_re, const float* __restrict__ C_im,
                         float* __restrict__ p_ar, float* __restrict__ p_ai,
                         float* __restrict__ p_wr, float* __restrict__ p_wi,
                         float* __restrict__ p_dr, float* __restrict__ p_di,
                         float* __restrict__ p_lr, float* __restrict__ p_li) {
  int i = blockIdx.x * blockDim.x + threadIdx.x;   // 0..32767, d = i>>6
  int d = i >> 6;
  float dt  = expf(log_dt[d]);
  float Are = -expf(log_A_real[i]);
  float Aim = A_imag[i];
  float dre = dt * Are, dim = dt * Aim;
  float em  = expf(dre);
  float abr = em * cosf(dim);
  float abi = em * sinf(dim);
  float nr = abr - 1.0f, ni = abi;
  float inv = 1.0f / (Are * Are + Aim * Aim);
  float br = (nr * Are + ni * Aim) * inv;
  float bi = (ni * Are - nr * Aim) * inv;
  float Br = B_re[i], Bi = B_im[i];
  float b2r = br * Br - bi * Bi;
  float b2i = br * Bi + bi * Br;
  float Cr = C_re[i], Ci = C_im[i];
  p_ar[i] = abr; p_ai[i] = abi;
  p_wr[i] = Cr * b2r - Ci * b2i;
  p_wi[i] = Cr * b2i + Ci * b2r;
  p_dr[i] = dre; p_di[i] = dim;
  float eL = expf(dre * 4096.0f);
  float phL = dim * 4096.0f;
  p_lr[i] = eL * cosf(phL);
  p_li[i] = eL * sinf(phL);
}

// ---- W_out fp32 -> bf16 -----------------------------------------------------
__global__ void k_wcvt(const float* __restrict__ w, ushort_t* __restrict__ wb, int n) {
  int i = blockIdx.x * blockDim.x + threadIdx.x;
  if (i < n) wb[i] = f2bf(w[i]);
}

// ---- u fp32 -> bf16 (8 elems/thread) ---------------------------------------
__global__ __launch_bounds__(256) void k_ucvt(const float* __restrict__ u,
                                              ushort_t* __restrict__ u_bf) {
  size_t i = (size_t)blockIdx.x * 256 + threadIdx.x;   // per 8 elems
  const float4* p = (const float4*)u + 2 * i;
  float4 a = p[0], b = p[1];
  uint4 v;
  v.x = (uint_t)f2bf(a.x) | ((uint_t)f2bf(a.y) << 16);
  v.y = (uint_t)f2bf(a.z) | ((uint_t)f2bf(a.w) << 16);
  v.z = (uint_t)f2bf(b.x) | ((uint_t)f2bf(b.y) << 16);
  v.w = (uint_t)f2bf(b.z) | ((uint_t)f2bf(b.w) << 16);
  ((uint4*)u_bf)[i] = v;
}

// ---- K1: H sums via MFMA ---------------------------------------------------
__global__ __launch_bounds__(256) void k_hgemm(
    const ushort_t* __restrict__ u_bf,
    const float* __restrict__ p_ar, const float* __restrict__ p_ai,
    const float* __restrict__ p_dr, const float* __restrict__ p_di,
    float2* __restrict__ Hbuf) {
  __shared__ ushort_t VLD[128][128];
  int d = blockIdx.x;
  int tid = threadIdx.x;
  int wv = tid >> 6, lane = tid & 63;
  int wm = wv >> 1, wn = wv & 1;
  int lrow = lane & 15, quad = lane >> 4;

  int m = tid & 127, chalf = tid >> 7;
  int nn = m >> 1, pp = m & 1;
  float ar = p_ar[d * 64 + nn], ai = p_ai[d * 64 + nn];
  float dr = p_dr[d * 64 + nn], di = p_di[d * 64 + nn];

  f32x4 acc[4][4];
#pragma unroll
  for (int mt = 0; mt < 4; ++mt)
#pragma unroll
    for (int nt = 0; nt < 4; ++nt) acc[mt][nt] = (f32x4){0.f, 0.f, 0.f, 0.f};

  for (int kt = 0; kt < 4; ++kt) {
    f2 z = cexp(dr, di, (float)(kt * 128 + chalf * 64));
#pragma unroll
    for (int g8 = 0; g8 < 8; ++g8) {
      ushort_t vals[8];
#pragma unroll
      for (int e = 0; e < 8; ++e) {
        vals[e] = f2bf(pp ? z.y : z.x);
        float zr = z.x * ar - z.y * ai;
        z.y = z.x * ai + z.y * ar;
        z.x = zr;
      }
      int g = (chalf * 64 + g8 * 8) >> 3;
      int gph = g ^ (m & 7);
      uint4 pk;
      pk.x = (uint_t)vals[0] | ((uint_t)vals[1] << 16);
      pk.y = (uint_t)vals[2] | ((uint_t)vals[3] << 16);
      pk.z = (uint_t)vals[4] | ((uint_t)vals[5] << 16);
      pk.w = (uint_t)vals[6] | ((uint_t)vals[7] << 16);
      *(uint4*)&VLD[m][gph << 3] = pk;
    }
    __syncthreads();
#pragma unroll
    for (int kb = 0; kb < 4; ++kb) {
      int kbase = kb * 32 + quad * 8;
      short8 af[4], bf[4];
#pragma unroll
      for (int mt = 0; mt < 4; ++mt) {
        int mrow = wm * 64 + mt * 16 + lrow;
        int gph = (kbase >> 3) ^ (mrow & 7);
        af[mt] = *(const short8*)&VLD[mrow][gph << 3];
      }
#pragma unroll
      for (int nt = 0; nt < 4; ++nt) {
        int col = wn * 64 + nt * 16 + lrow;
        int b = col >> 3, c = col & 7;
        bf[nt] = *(const short8*)(u_bf + (size_t)(b * 512 + d) * 4096 + c * 512 + kt * 128 + kbase);
      }
#pragma unroll
      for (int mt = 0; mt < 4; ++mt)
#pragma unroll
        for (int nt = 0; nt < 4; ++nt)
          acc[mt][nt] = __builtin_amdgcn_mfma_f32_16x16x32_bf16(af[mt], bf[nt], acc[mt][nt], 0, 0, 0);
    }
    __syncthreads();
  }
#pragma unroll
  for (int mt = 0; mt < 4; ++mt) {
#pragma unroll
    for (int nt = 0; nt < 4; ++nt) {
      int col = wn * 64 + nt * 16 + lrow;
      int b = col >> 3, c = col & 7;
      int m0 = wm * 64 + mt * 16 + quad * 4;
      int n0 = m0 >> 1;
      float4 v = {acc[mt][nt][0], acc[mt][nt][1], acc[mt][nt][2], acc[mt][nt][3]};
      *(float4*)((float*)(Hbuf + ((size_t)((b * 8 + c) * 512 + d)) * 64 + n0)) = v;
    }
  }
}

// ---- K2: kernel tail Kbuf[d][x] = K[3584+x]; x=511 carries +D[d] (diag = D*u)
__global__ __launch_bounds__(64) void k_kc(
    const float* __restrict__ p_ar, const float* __restrict__ p_ai,
    const float* __restrict__ p_wr, const float* __restrict__ p_wi,
    const float* __restrict__ p_dr, const float* __restrict__ p_di,
    const float* __restrict__ Dvec, ushort_t* __restrict__ Kbuf) {
  int d = blockIdx.x;
  int n = threadIdx.x;
  int i = d * 64 + n;
  float ar = p_ar[i], ai = p_ai[i];
  float wr = p_wr[i], wi = p_wi[i];
  float Dd = Dvec[d];
  f2 e = cexp(p_dr[i], p_di[i], 3584.0f);
  float zr = wr * e.x - wi * e.y;
  float zi = wr * e.y + wi * e.x;
  for (int x = 0; x < 512; ++x) {
    float s = zr;
#pragma unroll
    for (int off = 1; off < 64; off <<= 1) s += __shfl_xor(s, off, 64);
    if (n == 0) Kbuf[d * 512 + x] = f2bf(x == 511 ? s + Dd : s);
    float tr = zr * ar - zi * ai;
    zi = zr * ai + zi * ar;
    zr = tr;
  }
}

// ---- K3: seeds. s[c] = A^((7-c)S) * F[cS-1], F excl own chunk. --------------
__global__ __launch_bounds__(256) void k_seedpack(
    const float* __restrict__ p_dr, const float* __restrict__ p_di,
    const float2* __restrict__ Hbuf, ushort_t* __restrict__ seedB) {
  __shared__ ushort_t tile[128 * 128];
  int d = blockIdx.x;
  int tid = threadIdx.x;
  int n = tid >> 2;      // 0..63
  int bq = tid & 3;
  float dr = p_dr[d * 64 + n], di = p_di[d * 64 + n];
  f2 AS = cexp(dr, di, 512.0f);
  f2 R[8];
  R[0] = (f2){1.f, 0.f};
#pragma unroll
  for (int c = 1; c < 8; ++c)
    R[c] = (f2){R[c-1].x * AS.x - R[c-1].y * AS.y, R[c-1].x * AS.y + R[c-1].y * AS.x};
  for (int bb = 0; bb < 4; ++bb) {
    int b = bq * 4 + bb;
    f2 G = {0.f, 0.f};
#pragma unroll
    for (int c = 0; c < 8; ++c) {
      f2 T = R[7 - c];
      float sr = T.x * G.x - T.y * G.y;
      float si = T.x * G.y + T.y * G.x;
      int col = b * 8 + c;
      tile[col * 128 + 2 * n]     = f2bf(sr);
      tile[col * 128 + 2 * n + 1] = f2bf(si);
      float2 h = Hbuf[((size_t)((b * 8 + c) * 512 + d)) * 64 + n];
      G.x += R[c].x * h.x - R[c].y * h.y;
      G.y += R[c].x * h.y + R[c].y * h.x;
    }
  }
  __syncthreads();
  const uint4* src = (const uint4*)tile;
  uint4* dst = (uint4*)(seedB + (size_t)d * 16384);
  for (int k = tid; k < 2048; k += 256) dst[k] = src[k];
}

// ---- K4: per-d Toeplitz + seed GEMM (MFMA), writes yraw (d,b,l) bf16 --------
// 1D grid 2048: id -> d = ((id>>5)<<3)|(id&7), t0 = ((id>>3)&3)*128.
// (4 tq-blocks of a d are 8 apart and id%8==d%8 -> same XCD -> u-slice L2 reuse)
#define KRN 1048
__global__ __launch_bounds__(256) void k_conv(
    const ushort_t* __restrict__ u_bf, const ushort_t* __restrict__ Kbuf,
    const ushort_t* __restrict__ seedB,
    const float* __restrict__ p_ar, const float* __restrict__ p_ai,
    const float* __restrict__ p_wr, const float* __restrict__ p_wi,
    const float* __restrict__ p_dr, const float* __restrict__ p_di,
    ushort_t* __restrict__ yraw) {
  __shared__ ushort_t KRc[8][KRN];
  __shared__ ushort_t PLD[128][136];
  int id = blockIdx.x;
  int d = ((id >> 5) << 3) | (id & 7);
  int t0 = ((id >> 3) & 3) * 128;
  int tid = threadIdx.x;

  for (int e = tid; e < 8 * KRN; e += 256) {
    int r = e / KRN, x = e - r * KRN;
    int y = x + r;
    KRc[r][x] = (y < 512) ? Kbuf[d * 512 + y] : (ushort_t)0;
  }
  {
    int n = tid & 63, mh = tid >> 6;
    int i = d * 64 + n;
    float ar = p_ar[i], ai = p_ai[i];
    float wr = p_wr[i], wi = p_wi[i];
    int mtop = mh * 32 + 31;
    f2 E = cexp(p_dr[i], p_di[i], (float)(511 - t0 - mtop));
    float zr = wr * E.x - wi * E.y;
    float zi = wr * E.y + wi * E.x;
    for (int m = mtop; m >= mh * 32; --m) {
      PLD[m][2 * n]     = f2bf(zr);
      PLD[m][2 * n + 1] = f2bf(-zi);
      float tr = zr * ar - zi * ai;
      zi = zr * ai + zi * ar;
      zr = tr;
    }
  }
  __syncthreads();

  int wv = tid >> 6, lane = tid & 63;
  int wm = wv >> 1, wn = wv & 1;
  int lrow = lane & 15, quad = lane >> 4;
  f32x4 acc[4][4];
#pragma unroll
  for (int mt = 0; mt < 4; ++mt)
#pragma unroll
    for (int nt = 0; nt < 4; ++nt) acc[mt][nt] = (f32x4){0.f, 0.f, 0.f, 0.f};

  for (int kt = 0; kt < 16; ++kt) {
    int kbase = kt * 32 + quad * 8;
    short8 af[4], bf[4];
#pragma unroll
    for (int mt = 0; mt < 4; ++mt) {
      int mr = wm * 64 + mt * 16 + lrow;
      int idx = 511 - t0 - mr + kbase;
      int r = idx & 7, st = idx - r;
      af[mt] = *(const short8*)&KRc[r][st];
    }
#pragma unroll
    for (int nt = 0; nt < 4; ++nt) {
      int col = wn * 64 + nt * 16 + lrow;
      int b = col >> 3, c = col & 7;
      bf[nt] = *(const short8*)(u_bf + (size_t)(b * 512 + d) * 4096 + c * 512 + kbase);
    }
#pragma unroll
    for (int mt = 0; mt < 4; ++mt)
#pragma unroll
      for (int nt = 0; nt < 4; ++nt)
        acc[mt][nt] = __builtin_amdgcn_mfma_f32_16x16x32_bf16(af[mt], bf[nt], acc[mt][nt], 0, 0, 0);
  }
  for (int kt = 0; kt < 4; ++kt) {
    int k2 = kt * 32 + quad * 8;
    short8 af[4], bf[4];
#pragma unroll
    for (int mt = 0; mt < 4; ++mt)
      af[mt] = *(const short8*)&PLD[wm * 64 + mt * 16 + lrow][k2];
#pragma unroll
    for (int nt = 0; nt < 4; ++nt) {
      int col = wn * 64 + nt * 16 + lrow;
      bf[nt] = *(const short8*)(seedB + (size_t)d * 16384 + col * 128 + k2);
    }
#pragma unroll
    for (int mt = 0; mt < 4; ++mt)
#pragma unroll
      for (int nt = 0; nt < 4; ++nt)
        acc[mt][nt] = __builtin_amdgcn_mfma_f32_16x16x32_bf16(af[mt], bf[nt], acc[mt][nt], 0, 0, 0);
  }

#pragma unroll
  for (int mt = 0; mt < 4; ++mt) {
#pragma unroll
    for (int nt = 0; nt < 4; ++nt) {
      int col = wn * 64 + nt * 16 + lrow;
      int b = col >> 3, c = col & 7;
      int tau = t0 + wm * 64 + mt * 16 + quad * 4;
      uint_t lo = (uint_t)f2bf(acc[mt][nt][0]) | ((uint_t)f2bf(acc[mt][nt][1]) << 16);
      uint_t hi = (uint_t)f2bf(acc[mt][nt][2]) | ((uint_t)f2bf(acc[mt][nt][3]) << 16);
      uint2 vv = {lo, hi};
      *(uint2*)(yraw + (size_t)d * 65536 + b * 4096 + c * 512 + tau) = vv;
    }
  }
}

// ---- K5: exact gelu + transpose: yraw (d,b,l) -> yg (b,l,d) bf16 ------------
// (D*u already folded into conv diagonal)
__global__ __launch_bounds__(256) void k_tg(
    const ushort_t* __restrict__ yraw, ushort_t* __restrict__ yg) {
  __shared__ ushort_t tile[64][72];
  int blk = blockIdx.x;
  int b = blk >> 9, dg = (blk >> 6) & 7, lg = blk & 63;
  int d0 = dg * 64, l0 = lg * 64;
  int tid = threadIdx.x;
  int dd = tid >> 2, lc = (tid & 3) * 16;

  const ushort_t* yp = yraw + (size_t)(d0 + dd) * 65536 + b * 4096 + l0 + lc;
  uint4 A0 = *(const uint4*)yp;
  uint4 A1 = *(const uint4*)(yp + 8);
  uint_t w[8] = {A0.x, A0.y, A0.z, A0.w, A1.x, A1.y, A1.z, A1.w};
#pragma unroll
  for (int i2 = 0; i2 < 16; ++i2) {
    ushort_t bits = (i2 & 1) ? (ushort_t)(w[i2 >> 1] >> 16) : (ushort_t)(w[i2 >> 1] & 0xffff);
    float y = bf2f(bits);
    float g = 0.5f * y * (1.0f + erff(y * 0.70710678118654752f));
    int row = lc + i2;
    int col = (dd + ((row >> 3) & 7) * 8) & 63;
    tile[row][col] = f2bf(g);
  }
  __syncthreads();
  int lr = tid >> 2, dc = (tid & 3) * 16;
  int rot = ((lr >> 3) & 7) * 8;
  int o1 = (dc + rot) & 63;
  int o2 = (dc + 8 + rot) & 63;
  uint4 v1 = *(const uint4*)&tile[lr][o1];
  uint4 v2 = *(const uint4*)&tile[lr][o2];
  ushort_t* og = yg + (size_t)b * (4096 * 512) + (size_t)(l0 + lr) * 512 + d0 + dc;
  *(uint4*)og = v1;
  *(uint4*)(og + 8) = v2;
}

// ---- 1x1 conv (512->1024) + bias + GLU + sum-over-L, fused ------------------
// 1D grid 4096: id -> p=id>>8, m=(id>>5)&7, q=id&31; n0=(p*32+q)*128, mp0=m*64.
// id%8==q%8 -> all 8 m-blocks of an n-tile on one XCD (yg L2 reuse).
// LDS tiles XOR-granule swizzled ([.][64], granule 16B ^ (row&7)): conflict-free.
__global__ __launch_bounds__(256) void k_gemm(
    const ushort_t* __restrict__ wbf, const ushort_t* __restrict__ yg,
    const float* __restrict__ b_out, float* __restrict__ pooled) {
  __shared__ ushort_t lwa[64][64];
  __shared__ ushort_t lwg[64][64];
  __shared__ ushort_t ly[128][64];
  int tid = threadIdx.x;
  int id = blockIdx.x;
  int p = id >> 8, m = (id >> 5) & 7, q = id & 31;
  int mp0 = m * 64;
  int n0 = (p * 32 + q) * 128;
  int b = n0 >> 12;
  int wv = tid >> 6, lane = tid & 63;
  int mh = wv >> 1, nh = wv & 1;
  int lrow = lane & 15, quad = lane >> 4;
  f32x4 accA[2][4], accG[2][4];
#pragma unroll
  for (int mt = 0; mt < 2; ++mt)
#pragma unroll
    for (int nt = 0; nt < 4; ++nt) {
      accA[mt][nt] = (f32x4){0.f, 0.f, 0.f, 0.f};
      accG[mt][nt] = (f32x4){0.f, 0.f, 0.f, 0.f};
    }
  int srow = tid >> 2, scol = (tid & 3) * 16;
  int srow2 = tid >> 1, scol2 = (tid & 1) * 32;
  int s7 = srow & 7, s72 = srow2 & 7;
  int ga = scol >> 3, g2 = scol2 >> 3;
  for (int kc = 0; kc < 512; kc += 64) {
    const uint4* pa = (const uint4*)(wbf + (size_t)(mp0 + srow) * 512 + kc + scol);
    const uint4* pg = (const uint4*)(wbf + (size_t)(512 + mp0 + srow) * 512 + kc + scol);
    const uint4* py = (const uint4*)(yg + (size_t)(n0 + srow2) * 512 + kc + scol2);
    uint4 va0 = pa[0], va1 = pa[1];
    uint4 vg0 = pg[0], vg1 = pg[1];
    uint4 vy0 = py[0], vy1 = py[1], vy2 = py[2], vy3 = py[3];
    *(uint4*)&lwa[srow][((ga + 0) ^ s7) << 3] = va0;
    *(uint4*)&lwa[srow][((ga + 1) ^ s7) << 3] = va1;
    *(uint4*)&lwg[srow][((ga + 0) ^ s7) << 3] = vg0;
    *(uint4*)&lwg[srow][((ga + 1) ^ s7) << 3] = vg1;
    *(uint4*)&ly[srow2][((g2 + 0) ^ s72) << 3] = vy0;
    *(uint4*)&ly[srow2][((g2 + 1) ^ s72) << 3] = vy1;
    *(uint4*)&ly[srow2][((g2 + 2) ^ s72) << 3] = vy2;
    *(uint4*)&ly[srow2][((g2 + 3) ^ s72) << 3] = vy3;
    __syncthreads();
#pragma unroll
    for (int kb = 0; kb < 2; ++kb) {
      int kg = kb * 4 + quad;   // granule index of ko
      short8 bfv[4], af[2], gf[2];
#pragma unroll
      for (int nt = 0; nt < 4; ++nt) {
        int row = nh * 64 + nt * 16 + lrow;
        bfv[nt] = *(const short8*)&ly[row][(kg ^ (row & 7)) << 3];
      }
#pragma unroll
      for (int mt = 0; mt < 2; ++mt) {
        int row = mh * 32 + mt * 16 + lrow;
        af[mt] = *(const short8*)&lwa[row][(kg ^ (row & 7)) << 3];
        gf[mt] = *(const short8*)&lwg[row][(kg ^ (row & 7)) << 3];
      }
#pragma unroll
      for (int mt = 0; mt < 2; ++mt)
#pragma unroll
        for (int nt = 0; nt < 4; ++nt) {
          accA[mt][nt] = __builtin_amdgcn_mfma_f32_16x16x32_bf16(af[mt], bfv[nt], accA[mt][nt], 0, 0, 0);
          accG[mt][nt] = __builtin_amdgcn_mfma_f32_16x16x32_bf16(gf[mt], bfv[nt], accG[mt][nt], 0, 0, 0);
        }
    }
    __syncthreads();
  }
#pragma unroll
  for (int mt = 0; mt < 2; ++mt) {
#pragma unroll
    for (int reg = 0; reg < 4; ++reg) {
      int olocal = mh * 32 + mt * 16 + quad * 4 + reg;
      float ba = b_out[mp0 + olocal];
      float bg = b_out[512 + mp0 + olocal];
      float h = 0.f;
#pragma unroll
      for (int nt = 0; nt < 4; ++nt) {
        float a = accA[mt][nt][reg] + ba;
        float gv = accG[mt][nt][reg] + bg;
        h += a / (1.0f + __expf(-gv));
      }
#pragma unroll
      for (int off = 1; off < 16; off <<= 1) h += __shfl_xor(h, off, 16);
      if (lrow == 0) atomicAdd(&pooled[b * 512 + mp0 + olocal], h);
    }
  }
}

// ---- decoder ----------------------------------------------------------------
__global__ void k_final(const float* __restrict__ pooled, const float* __restrict__ W_dec,
                        const float* __restrict__ b_dec, float* __restrict__ out) {
  int b = blockIdx.x;
  int lane = threadIdx.x;
  float s = 0.f;
#pragma unroll
  for (int j = 0; j < 8; ++j) s += pooled[b * 512 + lane + 64 * j] * W_dec[lane + 64 * j];
#pragma unroll
  for (int off = 1; off < 64; off <<= 1) s += __shfl_xor(s, off, 64);
  if (lane == 0) out[b] = s * (1.0f / 4096.0f) + b_dec[0];
}

extern "C" void kernel_launch(void* const* d_in, const int* in_sizes, int n_in,
                              void* d_out, int out_size, void* d_ws, size_t ws_size,
                              hipStream_t stream) {
  const float* u          = (const float*)d_in[0];
  const float* log_dt     = (const float*)d_in[1];
  const float* log_A_real = (const float*)d_in[2];
  const float* A_imag     = (const float*)d_in[3];
  const float* B_re       = (const float*)d_in[4];
  const float* B_im       = (const float*)d_in[5];
  const float* C_re       = (const float*)d_in[6];
  const float* C_im       = (const float*)d_in[7];
  const float* Dv         = (const float*)d_in[8];
  const float* W_out      = (const float*)d_in[9];
  const float* b_out      = (const float*)d_in[10];
  const float* W_dec      = (const float*)d_in[11];
  const float* b_dec      = (const float*)d_in[12];

  float* ws = (float*)d_ws;
  float* p_ar = ws;
  float* p_ai = ws + 32768;
  float* p_wr = ws + 65536;
  float* p_wi = ws + 98304;
  float* p_dr = ws + 131072;
  float* p_di = ws + 163840;
  float* p_lr = ws + 196608;
  float* p_li = ws + 229376;
  float* pooled = (float*)((char*)d_ws + UOFF_POOLED);
  ushort_t* wbf   = (ushort_t*)((char*)d_ws + UOFF_WBF);
  ushort_t* u_bf  = (ushort_t*)((char*)d_ws + UOFF_UBF);
  ushort_t* yg    = (ushort_t*)((char*)d_ws + UOFF_UBF);    // alias: reused after k_conv
  ushort_t* yraw  = (ushort_t*)((char*)d_ws + UOFF_YRAW);
  float2*   Hbuf  = (float2*)((char*)d_ws + UOFF_YRAW);     // alias: dead before k_conv writes
  ushort_t* seedB = (ushort_t*)((char*)d_ws + UOFF_SEEDB);
  ushort_t* Kbuf  = (ushort_t*)((char*)d_ws + UOFF_KBUF);

  hipMemsetAsync(pooled, 0, 16 * 512 * sizeof(float), stream);
  k_params<<<128, 256, 0, stream>>>(log_dt, log_A_real, A_imag, B_re, B_im, C_re, C_im,
                                    p_ar, p_ai, p_wr, p_wi, p_dr, p_di, p_lr, p_li);
  k_wcvt<<<2048, 256, 0, stream>>>(W_out, wbf, 1024 * 512);
  k_ucvt<<<16384, 256, 0, stream>>>(u, u_bf);
  k_hgemm<<<512, 256, 0, stream>>>(u_bf, p_ar, p_ai, p_dr, p_di, Hbuf);
  k_kc<<<512, 64, 0, stream>>>(p_ar, p_ai, p_wr, p_wi, p_dr, p_di, Dv, Kbuf);
  k_seedpack<<<512, 256, 0, stream>>>(p_dr, p_di, Hbuf, seedB);
  k_conv<<<2048, 256, 0, stream>>>(u_bf, Kbuf, seedB,
                                   p_ar, p_ai, p_wr, p_wi, p_dr, p_di, yraw);
  k_tg<<<8192, 256, 0, stream>>>(yraw, yg);
  k_gemm<<<4096, 256, 0, stream>>>(wbf, yg, b_out, pooled);
  k_final<<<16, 64, 0, stream>>>(pooled, W_dec, b_dec, (float*)d_out);
}